// Round 1
// baseline (3069.002 us; speedup 1.0000x reference)
//
#include <hip/hip_runtime.h>
#include <hip/hip_bf16.h>

#define B_N 4
#define C_N 128
#define HW_ 256
#define NPIX (HW_ * HW_)          // 65536
#define NK 396
#define KPADD 65                  // dwords per K row (130 ushorts, stride 1 mod 32)
#define QPADD 66                  // dwords per Q row (132 ushorts)
#define APADD 65                  // dwords per agg row (130 ushorts)
#define OUT_MAIN ((size_t)B_N * C_N * NPIX)      // 33554432
#define P12_OFF OUT_MAIN
#define P6_OFF  (P12_OFF + (size_t)B_N * C_N * 144)

// LDS dword offsets for attn kernel
#define LDS_K 0                    // 396*65 = 25740 dw (reused as float W[16384])
#define LDS_Q 25740                // 64*66  = 4224 dw
#define LDS_A 29964                // 64*65  = 4160 dw
#define LDS_P 34124                // 8*400  = 3200 dw
#define LDS_TOTAL_BYTES ((34124 + 3200) * 4)   // 149296

// ---------------- kernel 1: multi-scale adaptive avg pools ----------------
__global__ __launch_bounds__(256) void pool_kernel(
    const float* __restrict__ x5, __hip_bfloat16* __restrict__ wsK,
    float* __restrict__ out)
{
  __shared__ float yh[54][257];
  const int bc = blockIdx.x;          // 0..511 = b*128+c
  const int b  = bc >> 7;
  const int c  = bc & 127;
  const float* plane = x5 + (size_t)bc * NPIX;
  const int w = threadIdx.x;          // 0..255

  // Phase A: h-pooled rows for every scale (matches reference Ph pass)
  #pragma unroll
  for (int sc = 0; sc < 7; ++sc) {
    const int o    = (sc==0)?16:(sc==1)?12:(sc==2)?9:(sc==3)?7:(sc==4)?6:(sc==5)?3:1;
    const int rofs = (sc==0)?0 :(sc==1)?16:(sc==2)?28:(sc==3)?37:(sc==4)?44:(sc==5)?50:53;
    for (int i = 0; i < o; ++i) {
      const int s = (i * HW_) / o;
      const int e = ((i + 1) * HW_ + o - 1) / o;
      float sum = 0.f;
      for (int h = s; h < e; ++h) sum += plane[h * HW_ + w];
      yh[rofs + i][w] = sum * (1.0f / (float)(e - s));
    }
  }
  __syncthreads();

  // Phase B: w-pool each row -> 576 outputs total
  for (int r = threadIdx.x; r < 576; r += 256) {
    int rr = r;
    int o, ro, kbase, dst;   // dst: 0=Key, 1=p12, 2=p6
    if      (rr < 256) { o = 16; ro = 0;  kbase = 140; dst = 0; }
    else if (rr < 400) { o = 12; ro = 16; kbase = 0;   dst = 1; rr -= 256; }
    else if (rr < 481) { o = 9;  ro = 28; kbase = 10;  dst = 0; rr -= 400; }
    else if (rr < 530) { o = 7;  ro = 37; kbase = 91;  dst = 0; rr -= 481; }
    else if (rr < 566) { o = 6;  ro = 44; kbase = 0;   dst = 2; rr -= 530; }
    else if (rr < 575) { o = 3;  ro = 50; kbase = 0;   dst = 0; rr -= 566; }
    else               { o = 1;  ro = 53; kbase = 9;   dst = 0; rr = 0;   }
    const int i = rr / o;
    const int j = rr - i * o;
    const int s = (j * HW_) / o;
    const int e = ((j + 1) * HW_ + o - 1) / o;
    float sum = 0.f;
    const float* row = yh[ro + i];
    for (int wq = s; wq < e; ++wq) sum += row[wq];
    const float v = sum * (1.0f / (float)(e - s));
    if (dst == 1) {
      out[P12_OFF + (size_t)bc * 144 + rr] = v;
    } else if (dst == 2) {
      out[P6_OFF + (size_t)bc * 36 + rr] = v;
    } else {
      wsK[((size_t)b * NK + kbase + rr) * C_N + c] = __float2bfloat16(v);
    }
  }
}

// -------- kernel 2: fused attention + 1x1 conv + bias + residual --------
__global__ __launch_bounds__(512) void attn_kernel(
    const float* __restrict__ x5, const __hip_bfloat16* __restrict__ wsK,
    const float* __restrict__ W_out, const float* __restrict__ b_out,
    float* __restrict__ out)
{
  extern __shared__ unsigned smem[];
  unsigned* Kdw = smem + LDS_K;
  unsigned* Qdw = smem + LDS_Q;
  unsigned* Adw = smem + LDS_A;
  float*    Pls = (float*)(smem + LDS_P);

  const int tid  = threadIdx.x;
  const int b    = blockIdx.x >> 10;
  const int pix0 = (blockIdx.x & 1023) << 6;

  // stage K [396][130 bf16] (conflict-free padded)
  {
    const unsigned* src = (const unsigned*)(wsK + (size_t)b * NK * C_N);
    for (int idx = tid; idx < NK * C_N / 2; idx += 512) {
      const int k  = idx >> 6;
      const int cp = idx & 63;
      Kdw[k * KPADD + cp] = src[idx];
    }
  }
  // stage Q tile [64 pix][132 bf16]
  {
    const int pix = tid & 63;
    for (int c = tid >> 6; c < C_N; c += 8) {
      const float v = x5[((size_t)(b * C_N + c)) * NPIX + pix0 + pix];
      ((__hip_bfloat16*)Qdw)[pix * (QPADD * 2) + c] = __float2bfloat16(v);
    }
  }
  __syncthreads();

  const int wv = tid >> 6, lane = tid & 63;
  float* pw = Pls + wv * 400;
  const float SC  = 0.044194173824159216f;   // 512**-0.5
  const float L2E = 1.4426950408889634f;

  for (int pi = 0; pi < 8; ++pi) {
    const int lp = wv * 8 + pi;
    const unsigned* qrow = Qdw + lp * QPADD;
    // ---- scores: lane owns k = lane + 64*j ----
    float s[7];
    #pragma unroll
    for (int j = 0; j < 7; ++j) s[j] = 0.f;
    for (int cp = 0; cp < 64; ++cp) {
      const unsigned qp = qrow[cp];               // LDS broadcast
      const float q0 = __uint_as_float(qp << 16);
      const float q1 = __uint_as_float(qp & 0xffff0000u);
      #pragma unroll
      for (int j = 0; j < 6; ++j) {
        const unsigned kp = Kdw[(lane + 64 * j) * KPADD + cp];
        s[j] += q0 * __uint_as_float(kp << 16);
        s[j] += q1 * __uint_as_float(kp & 0xffff0000u);
      }
    }
    if (lane < 12) {
      for (int cp = 0; cp < 64; ++cp) {
        const unsigned qp = qrow[cp];
        const unsigned kp = Kdw[(lane + 384) * KPADD + cp];
        s[6] += __uint_as_float(qp << 16) * __uint_as_float(kp << 16);
        s[6] += __uint_as_float(qp & 0xffff0000u) * __uint_as_float(kp & 0xffff0000u);
      }
    }
    // ---- softmax over 396 (wave-wide) ----
    float m = -1e30f;
    #pragma unroll
    for (int j = 0; j < 6; ++j) { s[j] *= SC; m = fmaxf(m, s[j]); }
    s[6] = (lane < 12) ? s[6] * SC : -1e30f;
    m = fmaxf(m, s[6]);
    #pragma unroll
    for (int off = 1; off < 64; off <<= 1) m = fmaxf(m, __shfl_xor(m, off));
    float sum = 0.f;
    float p[7];
    #pragma unroll
    for (int j = 0; j < 7; ++j) { p[j] = exp2f((s[j] - m) * L2E); sum += p[j]; }
    #pragma unroll
    for (int off = 1; off < 64; off <<= 1) sum += __shfl_xor(sum, off);
    const float inv = 1.0f / sum;
    #pragma unroll
    for (int j = 0; j < 6; ++j) pw[lane + 64 * j] = p[j];
    if (lane < 12) pw[384 + lane] = p[6];
    // ---- agg: lane owns c = 2*lane, 2*lane+1 ----
    float a0 = 0.f, a1 = 0.f;
    for (int k = 0; k < NK; ++k) {
      const float pk = pw[k];                    // broadcast
      const unsigned kp = Kdw[k * KPADD + lane]; // conflict-free
      a0 += pk * __uint_as_float(kp << 16);
      a1 += pk * __uint_as_float(kp & 0xffff0000u);
    }
    a0 *= inv; a1 *= inv;
    const __hip_bfloat16 h0 = __float2bfloat16(a0);
    const __hip_bfloat16 h1 = __float2bfloat16(a1);
    const unsigned u0 = *(const unsigned short*)&h0;
    const unsigned u1 = *(const unsigned short*)&h1;
    Adw[lp * APADD + lane] = (u1 << 16) | u0;
  }
  __syncthreads();

  // reuse K region for W_out (fp32, 64 KB)
  {
    float4* dst = (float4*)Kdw;
    const float4* src = (const float4*)W_out;
    for (int idx = tid; idx < 16384 / 4; idx += 512) dst[idx] = src[idx];
  }
  __syncthreads();

  // ---- 1x1 conv + bias + residual; lane = pixel, wave owns 16 o's ----
  {
    const float* Wl = (const float*)Kdw;
    for (int j = 0; j < 16; ++j) {
      const int o = wv * 16 + j;
      const float bias = b_out[o];
      const float* wrow = Wl + o * C_N;
      float acc = 0.f;
      for (int cp = 0; cp < 64; ++cp) {
        const float2 wp = ((const float2*)wrow)[cp];   // broadcast
        const unsigned ap = Adw[lane * APADD + cp];    // stride 65 dw: conflict-free
        acc += wp.x * __uint_as_float(ap << 16);
        acc += wp.y * __uint_as_float(ap & 0xffff0000u);
      }
      const size_t oi = ((size_t)(b * C_N + o)) * NPIX + pix0 + lane;
      out[oi] = acc + bias + x5[oi];
    }
  }
}

extern "C" void kernel_launch(void* const* d_in, const int* in_sizes, int n_in,
                              void* d_out, int out_size, void* d_ws, size_t ws_size,
                              hipStream_t stream) {
  const float* x5    = (const float*)d_in[0];
  const float* W_out = (const float*)d_in[1];
  const float* b_out = (const float*)d_in[2];
  float* out = (float*)d_out;
  __hip_bfloat16* wsK = (__hip_bfloat16*)d_ws;   // 4*396*128 bf16 = 405504 B

  pool_kernel<<<512, 256, 0, stream>>>(x5, wsK, out);

  hipFuncSetAttribute((const void*)attn_kernel,
                      hipFuncAttributeMaxDynamicSharedMemorySize, LDS_TOTAL_BYTES);
  attn_kernel<<<B_N * 1024, 512, LDS_TOTAL_BYTES, stream>>>(x5, wsK, W_out, b_out, out);
}

// Round 2
// 1145.956 us; speedup vs baseline: 2.6781x; 2.6781x over previous
//
#include <hip/hip_runtime.h>
#include <hip/hip_bf16.h>

typedef short bf16x8 __attribute__((ext_vector_type(8)));
typedef float f32x4  __attribute__((ext_vector_type(4)));
typedef unsigned short ushort_t;

#define B_N 4
#define C_N 128
#define HW_ 256
#define NPIX (HW_ * HW_)          // 65536
#define NK 396
#define NKP 416                   // keys padded for MFMA (16|NKP, 32|NKP)
#define OUT_MAIN ((size_t)B_N * C_N * NPIX)
#define P12_OFF OUT_MAIN
#define P6_OFF  (P12_OFF + (size_t)B_N * C_N * 144)

// ---- LDS arena (bytes). Phase 1: K[416][136]bf16 @0 + Q[64][136]bf16 @113152.
// Phase 2: VT[128][424]bf16 @0 + P[64][424]bf16 @108544.
// Phase 3: W[128][136]bf16 @0 + AG[64][136]bf16 @108544.
#define K_STRIDE  272
#define QOFF      113152
#define Q_STRIDE  272
#define VT_STRIDE 848
#define POFF      108544
#define P_STRIDE  848
#define AGOFF     108544
#define AG_STRIDE 272
#define LDS_BYTES 162816

static __device__ __forceinline__ ushort_t f2bf(float x) {
  __hip_bfloat16 h = __float2bfloat16(x);
  return *(ushort_t*)&h;
}

// ---------------- kernel 1: multi-scale adaptive avg pools ----------------
__global__ __launch_bounds__(256) void pool_kernel(
    const float* __restrict__ x5, ushort_t* __restrict__ wsK,
    ushort_t* __restrict__ wsKT, float* __restrict__ out)
{
  __shared__ float yh[54][257];
  const int bc = blockIdx.x;          // b*128+c
  const int b  = bc >> 7;
  const int c  = bc & 127;
  const float* plane = x5 + (size_t)bc * NPIX;
  const int w = threadIdx.x;

  #pragma unroll
  for (int sc = 0; sc < 7; ++sc) {
    const int o    = (sc==0)?16:(sc==1)?12:(sc==2)?9:(sc==3)?7:(sc==4)?6:(sc==5)?3:1;
    const int rofs = (sc==0)?0 :(sc==1)?16:(sc==2)?28:(sc==3)?37:(sc==4)?44:(sc==5)?50:53;
    for (int i = 0; i < o; ++i) {
      const int s = (i * HW_) / o;
      const int e = ((i + 1) * HW_ + o - 1) / o;
      float sum = 0.f;
      for (int h = s; h < e; ++h) sum += plane[h * HW_ + w];
      yh[rofs + i][w] = sum * (1.0f / (float)(e - s));
    }
  }
  __syncthreads();

  // zero the key-padding of wsKT (keys 396..415)
  if (threadIdx.x < NKP - NK) wsKT[(size_t)bc * NKP + NK + threadIdx.x] = 0;

  for (int r = threadIdx.x; r < 576; r += 256) {
    int rr = r;
    int o, ro, kbase, dst;   // dst: 0=Key, 1=p12, 2=p6
    if      (rr < 256) { o = 16; ro = 0;  kbase = 140; dst = 0; }
    else if (rr < 400) { o = 12; ro = 16; kbase = 0;   dst = 1; rr -= 256; }
    else if (rr < 481) { o = 9;  ro = 28; kbase = 10;  dst = 0; rr -= 400; }
    else if (rr < 530) { o = 7;  ro = 37; kbase = 91;  dst = 0; rr -= 481; }
    else if (rr < 566) { o = 6;  ro = 44; kbase = 0;   dst = 2; rr -= 530; }
    else if (rr < 575) { o = 3;  ro = 50; kbase = 0;   dst = 0; rr -= 566; }
    else               { o = 1;  ro = 53; kbase = 9;   dst = 0; rr = 0;   }
    const int i = rr / o;
    const int j = rr - i * o;
    const int s = (j * HW_) / o;
    const int e = ((j + 1) * HW_ + o - 1) / o;
    float sum = 0.f;
    const float* row = yh[ro + i];
    for (int wq = s; wq < e; ++wq) sum += row[wq];
    const float v = sum * (1.0f / (float)(e - s));
    if (dst == 1) {
      out[P12_OFF + (size_t)bc * 144 + rr] = v;
    } else if (dst == 2) {
      out[P6_OFF + (size_t)bc * 36 + rr] = v;
    } else {
      const int key = kbase + rr;
      const ushort_t bv = f2bf(v);
      wsK [((size_t)b * NK + key) * C_N + c] = bv;   // [b][key][c]
      wsKT[(size_t)bc * NKP + key]           = bv;   // [b][c][key]
    }
  }
}

// -------- kernel 2: MFMA attention + 1x1 conv + bias + residual --------
__global__ __launch_bounds__(256, 1) void attn_kernel(
    const float* __restrict__ x5, const ushort_t* __restrict__ wsK,
    const ushort_t* __restrict__ wsKT, const float* __restrict__ W_out,
    const float* __restrict__ b_out, float* __restrict__ out)
{
  extern __shared__ char smem[];
  const int tid  = threadIdx.x;
  const int b    = blockIdx.x >> 10;
  const int pix0 = (blockIdx.x & 1023) << 6;
  const int lane = tid & 63, wv = tid >> 6;
  const int l15  = lane & 15, l4 = lane >> 4;

  // ---- stage K [416 keys][136 bf16]; rows >=396 zeroed ----
  {
    const unsigned* src = (const unsigned*)(wsK + (size_t)b * NK * C_N);
    for (int i = tid; i < NKP * 64; i += 256) {
      const int row = i >> 6, dw = i & 63;
      const unsigned v = (row < NK) ? src[i] : 0u;
      *(unsigned*)(smem + row * K_STRIDE + dw * 4) = v;
    }
  }
  // ---- stage Q [64 pix][136 bf16] (transpose from x5) ----
  {
    const int pix = tid & 63;
    for (int c = tid >> 6; c < C_N; c += 4) {
      const float v = x5[(((size_t)(b * C_N + c)) << 16) + pix0 + pix];
      *(ushort_t*)(smem + QOFF + pix * Q_STRIDE + c * 2) = f2bf(v);
    }
  }
  __syncthreads();

  // ---- scores: each wave 16 pixels x 416 keys, K=128 ----
  bf16x8 qf[4];
  #pragma unroll
  for (int kc = 0; kc < 4; ++kc)
    qf[kc] = *(const bf16x8*)(smem + QOFF + (wv*16 + l15) * Q_STRIDE + kc*64 + l4*16);

  f32x4 acc[26];
  #pragma unroll
  for (int nt = 0; nt < 26; ++nt) acc[nt] = (f32x4){0.f, 0.f, 0.f, 0.f};
  #pragma unroll
  for (int nt = 0; nt < 26; ++nt) {
    #pragma unroll
    for (int kc = 0; kc < 4; ++kc) {
      const bf16x8 kf = *(const bf16x8*)(smem + (nt*16 + l15) * K_STRIDE + kc*64 + l4*16);
      acc[nt] = __builtin_amdgcn_mfma_f32_16x16x32_bf16(qf[kc], kf, acc[nt], 0, 0, 0);
    }
  }

  // ---- scale + mask + softmax (row = pixel, spread over 16 lanes x 26 tiles) ----
  const float SC  = 0.044194173824159216f;   // 512**-0.5
  const float L2E = 1.4426950408889634f;
  #pragma unroll
  for (int nt = 0; nt < 26; ++nt) {
    const bool ok = (nt * 16 + l15) < NK;
    #pragma unroll
    for (int q = 0; q < 4; ++q)
      acc[nt][q] = ok ? acc[nt][q] * SC : -1e30f;
  }
  float inv[4];
  #pragma unroll
  for (int q = 0; q < 4; ++q) {
    float m = -1e30f;
    #pragma unroll
    for (int nt = 0; nt < 26; ++nt) m = fmaxf(m, acc[nt][q]);
    m = fmaxf(m, __shfl_xor(m, 1));
    m = fmaxf(m, __shfl_xor(m, 2));
    m = fmaxf(m, __shfl_xor(m, 4));
    m = fmaxf(m, __shfl_xor(m, 8));
    float s = 0.f;
    #pragma unroll
    for (int nt = 0; nt < 26; ++nt) {
      const float p = exp2f((acc[nt][q] - m) * L2E);
      acc[nt][q] = p;
      s += p;
    }
    s += __shfl_xor(s, 1);
    s += __shfl_xor(s, 2);
    s += __shfl_xor(s, 4);
    s += __shfl_xor(s, 8);
    inv[q] = 1.f / s;
  }
  __syncthreads();   // everyone done reading K/Q

  // ---- stage VT [128 c][424 keys] bf16 + write normalized P [64 pix][424] ----
  {
    const unsigned* srcT = (const unsigned*)(wsKT + (size_t)b * C_N * NKP);
    for (int c = tid >> 6; c < C_N; c += 4)
      for (int dw = lane; dw < 208; dw += 64)
        *(unsigned*)(smem + c * VT_STRIDE + dw * 4) = srcT[c * 208 + dw];
  }
  #pragma unroll
  for (int nt = 0; nt < 26; ++nt) {
    #pragma unroll
    for (int q = 0; q < 4; ++q) {
      *(ushort_t*)(smem + POFF + (wv*16 + l4*4 + q) * P_STRIDE + (nt*16 + l15) * 2) =
          f2bf(acc[nt][q] * inv[q]);
    }
  }
  __syncthreads();

  // ---- PV: agg[64 pix][128 c] = P * V ----
  f32x4 acc2[8];
  #pragma unroll
  for (int ct = 0; ct < 8; ++ct) acc2[ct] = (f32x4){0.f, 0.f, 0.f, 0.f};
  #pragma unroll
  for (int kc = 0; kc < 13; ++kc) {
    const bf16x8 pa = *(const bf16x8*)(smem + POFF + (wv*16 + l15) * P_STRIDE + kc*64 + l4*16);
    #pragma unroll
    for (int ct = 0; ct < 8; ++ct) {
      const bf16x8 vb = *(const bf16x8*)(smem + (ct*16 + l15) * VT_STRIDE + kc*64 + l4*16);
      acc2[ct] = __builtin_amdgcn_mfma_f32_16x16x32_bf16(pa, vb, acc2[ct], 0, 0, 0);
    }
  }
  __syncthreads();

  // ---- stage W [128 o][136 bf16] + write AG [64 pix][136 bf16] ----
  {
    const float2* wsrc = (const float2*)W_out;
    for (int i = tid; i < C_N * 64; i += 256) {
      const float2 w = wsrc[i];
      const unsigned pk = ((unsigned)f2bf(w.y) << 16) | f2bf(w.x);
      *(unsigned*)(smem + (i >> 6) * K_STRIDE + (i & 63) * 4) = pk;
    }
  }
  #pragma unroll
  for (int ct = 0; ct < 8; ++ct) {
    #pragma unroll
    for (int q = 0; q < 4; ++q) {
      *(ushort_t*)(smem + AGOFF + (wv*16 + l4*4 + q) * AG_STRIDE + (ct*16 + l15) * 2) =
          f2bf(acc2[ct][q]);
    }
  }
  __syncthreads();

  // ---- conv: D[o][pix] = W * agg^T, coalesced store + bias + residual ----
  f32x4 acc3[2][4];
  #pragma unroll
  for (int rt = 0; rt < 2; ++rt)
    #pragma unroll
    for (int pt = 0; pt < 4; ++pt) acc3[rt][pt] = (f32x4){0.f, 0.f, 0.f, 0.f};
  #pragma unroll
  for (int kc = 0; kc < 4; ++kc) {
    const bf16x8 wa0 = *(const bf16x8*)(smem + (wv*32      + l15) * K_STRIDE + kc*64 + l4*16);
    const bf16x8 wa1 = *(const bf16x8*)(smem + (wv*32 + 16 + l15) * K_STRIDE + kc*64 + l4*16);
    #pragma unroll
    for (int pt = 0; pt < 4; ++pt) {
      const bf16x8 ab = *(const bf16x8*)(smem + AGOFF + (pt*16 + l15) * AG_STRIDE + kc*64 + l4*16);
      acc3[0][pt] = __builtin_amdgcn_mfma_f32_16x16x32_bf16(wa0, ab, acc3[0][pt], 0, 0, 0);
      acc3[1][pt] = __builtin_amdgcn_mfma_f32_16x16x32_bf16(wa1, ab, acc3[1][pt], 0, 0, 0);
    }
  }
  #pragma unroll
  for (int rt = 0; rt < 2; ++rt) {
    #pragma unroll
    for (int q = 0; q < 4; ++q) {
      const int o = wv*32 + rt*16 + l4*4 + q;
      const float bias = b_out[o];
      #pragma unroll
      for (int pt = 0; pt < 4; ++pt) {
        const size_t idx = (((size_t)(b * C_N + o)) << 16) + pix0 + pt*16 + l15;
        out[idx] = acc3[rt][pt][q] + bias + x5[idx];
      }
    }
  }
}

extern "C" void kernel_launch(void* const* d_in, const int* in_sizes, int n_in,
                              void* d_out, int out_size, void* d_ws, size_t ws_size,
                              hipStream_t stream) {
  const float* x5    = (const float*)d_in[0];
  const float* W_out = (const float*)d_in[1];
  const float* b_out = (const float*)d_in[2];
  float* out = (float*)d_out;
  // workspace: wsK [4][396][128] bf16 = 405504 B, wsKT [4][128][416] bf16 = 425984 B
  ushort_t* wsK  = (ushort_t*)d_ws;
  ushort_t* wsKT = (ushort_t*)((char*)d_ws + (size_t)B_N * NK * C_N * 2);

  pool_kernel<<<512, 256, 0, stream>>>(x5, wsK, wsKT, out);

  hipFuncSetAttribute((const void*)attn_kernel,
                      hipFuncAttributeMaxDynamicSharedMemorySize, LDS_BYTES);
  attn_kernel<<<B_N * 1024, 256, LDS_BYTES, stream>>>(x5, wsK, wsKT, W_out, b_out, out);
}

// Round 3
// 470.249 us; speedup vs baseline: 6.5263x; 2.4369x over previous
//
#include <hip/hip_runtime.h>
#include <hip/hip_bf16.h>

typedef short bf16x8 __attribute__((ext_vector_type(8)));
typedef float f32x4  __attribute__((ext_vector_type(4)));
typedef unsigned short u16;

#define B_N 4
#define C_N 128
#define HW_ 256
#define NPIX 65536
#define NK 396
#define NKP 416
#define OUT_MAIN ((size_t)B_N * C_N * NPIX)
#define P12_OFF OUT_MAIN
#define P6_OFF  (P12_OFF + (size_t)B_N * C_N * 144)

// attn LDS arena: P/Q/outF region @0 (64*832=53248), AG @53248 (64*256=16384),
// xchg @69632 (1KB). total 70656 -> 2 blocks/CU.
#define P_STR   832
#define AG_OFF  53248
#define AG_STR  256
#define XC_OFF  69632
#define LDS_BYTES 70656

static __device__ __forceinline__ u16 f2bf(float x) {
  __hip_bfloat16 h = __float2bfloat16(x);
  return *(u16*)&h;
}

// ---------------- kernel 1: multi-scale adaptive avg pools (single-pass) ----
__global__ __launch_bounds__(256) void pool_kernel(
    const float* __restrict__ x5, u16* __restrict__ wsK,
    u16* __restrict__ wsKT, float* __restrict__ out)
{
  __shared__ float yh[54][257];
  const int bc = blockIdx.x;          // b*128+c
  const int b  = bc >> 7;
  const int c  = bc & 127;
  const float* plane = x5 + (size_t)bc * NPIX;
  const int w = threadIdx.x;

  const int os_[7] = {16,12,9,7,6,3,1};
  const int ro_[7] = {0,16,28,37,44,50,53};
  float acc[7], acc2[7];
  int r_[7], e_[7], s2_[7];
  #pragma unroll
  for (int s = 0; s < 7; ++s) {
    acc[s] = 0.f; acc2[s] = 0.f; r_[s] = 0;
    e_[s]  = (HW_ + os_[s] - 1) / os_[s];
    s2_[s] = HW_ / os_[s];
  }
  #pragma unroll 4
  for (int h = 0; h < HW_; ++h) {
    const float v = plane[h * HW_ + w];
    #pragma unroll
    for (int s = 0; s < 7; ++s) {
      acc[s] += v;
      if (h >= s2_[s]) acc2[s] += v;
      if (h + 1 == e_[s]) {
        const int st = (r_[s] * HW_) / os_[s];
        yh[ro_[s] + r_[s]][w] = acc[s] * (1.0f / (float)(e_[s] - st));
        r_[s]++;
        acc[s] = acc2[s]; acc2[s] = 0.f;
        e_[s]  = ((r_[s] + 1) * HW_ + os_[s] - 1) / os_[s];
        s2_[s] = ((r_[s] + 1) * HW_) / os_[s];
      }
    }
  }
  __syncthreads();

  // zero key-padding 396..415 in both workspaces
  if (threadIdx.x < NKP - NK) {
    wsK [((size_t)b * NKP + NK + threadIdx.x) * C_N + c] = 0;
    wsKT[(size_t)bc * NKP + NK + threadIdx.x] = 0;
  }

  for (int r = threadIdx.x; r < 576; r += 256) {
    int rr = r;
    int o, ro, kbase, dst;   // dst: 0=Key, 1=p12, 2=p6
    if      (rr < 256) { o = 16; ro = 0;  kbase = 140; dst = 0; }
    else if (rr < 400) { o = 12; ro = 16; kbase = 0;   dst = 1; rr -= 256; }
    else if (rr < 481) { o = 9;  ro = 28; kbase = 10;  dst = 0; rr -= 400; }
    else if (rr < 530) { o = 7;  ro = 37; kbase = 91;  dst = 0; rr -= 481; }
    else if (rr < 566) { o = 6;  ro = 44; kbase = 0;   dst = 2; rr -= 530; }
    else if (rr < 575) { o = 3;  ro = 50; kbase = 0;   dst = 0; rr -= 566; }
    else               { o = 1;  ro = 53; kbase = 9;   dst = 0; rr = 0;   }
    const int i = rr / o;
    const int j = rr - i * o;
    const int s = (j * HW_) / o;
    const int e = ((j + 1) * HW_ + o - 1) / o;
    float sum = 0.f;
    const float* row = yh[ro + i];
    for (int wq = s; wq < e; ++wq) sum += row[wq];
    const float v = sum * (1.0f / (float)(e - s));
    if (dst == 1) {
      out[P12_OFF + (size_t)bc * 144 + rr] = v;
    } else if (dst == 2) {
      out[P6_OFF + (size_t)bc * 36 + rr] = v;
    } else {
      const int key = kbase + rr;
      const u16 bv = f2bf(v);
      wsK [((size_t)b * NKP + key) * C_N + c] = bv;   // [b][key][c]
      wsKT[(size_t)bc * NKP + key]            = bv;   // [b][c][key]
    }
  }
}

// -------- kernel 2: MFMA attention + 1x1 conv + bias + residual --------
__global__ __launch_bounds__(512, 4) void attn_kernel(
    const float* __restrict__ x5, const u16* __restrict__ wsK,
    const u16* __restrict__ wsKT, const float* __restrict__ W_out,
    const float* __restrict__ b_out, float* __restrict__ out)
{
  extern __shared__ char smem[];
  const int tid  = threadIdx.x;
  const int b    = blockIdx.x >> 10;
  const int pix0 = (blockIdx.x & 1023) << 6;
  const int lane = tid & 63, wv = tid >> 6;
  const int l15  = lane & 15, l4 = lane >> 4;
  const int pg   = wv >> 1, half = wv & 1;

  const u16* wsKb  = wsK  + (size_t)b * NKP * C_N;
  const u16* wsKTb = wsKT + (size_t)b * C_N * NKP;

  // ---- stage Q: rows [64 pix] x 128c bf16 in P region, xor-swizzled ----
  {
    const int p4 = (tid & 15) * 4;
    #pragma unroll
    for (int pass = 0; pass < 4; ++pass) {
      const int c = (tid >> 4) + pass * 32;
      const float4 v = *(const float4*)(x5 + (((size_t)(b * C_N + c)) << 16) + pix0 + p4);
      #pragma unroll
      for (int j = 0; j < 4; ++j) {
        const int pix = p4 + j;
        const int a = pix * P_STR + c * 2;
        *(u16*)(smem + (a ^ ((pix & 7) << 4))) = f2bf(((const float*)&v)[j]);
      }
    }
  }
  __syncthreads();

  // ---- scores: wave (pg, half): 16 pix x 208 keys, K-frags from global ----
  bf16x8 qf[4];
  const int qpix = pg * 16 + l15;
  #pragma unroll
  for (int kc = 0; kc < 4; ++kc) {
    const int a = qpix * P_STR + kc * 64 + l4 * 16;
    qf[kc] = *(const bf16x8*)(smem + (a ^ ((l15 & 7) << 4)));
  }
  f32x4 acc[13];
  #pragma unroll
  for (int nt = 0; nt < 13; ++nt) acc[nt] = (f32x4){0.f, 0.f, 0.f, 0.f};
  {
    const u16* kbase = wsKb + (size_t)(half * 208 + l15) * C_N + l4 * 8;
    #pragma unroll
    for (int nt = 0; nt < 13; ++nt) {
      const u16* kr = kbase + nt * 16 * C_N;
      #pragma unroll
      for (int kc = 0; kc < 4; ++kc) {
        const bf16x8 kf = *(const bf16x8*)(kr + kc * 32);
        acc[nt] = __builtin_amdgcn_mfma_f32_16x16x32_bf16(qf[kc], kf, acc[nt], 0, 0, 0);
      }
    }
  }

  // ---- scale + mask + per-half softmax ----
  const float SC  = 0.044194173824159216f;   // 512**-0.5
  const float L2E = 1.4426950408889634f;
  #pragma unroll
  for (int nt = 0; nt < 13; ++nt) {
    const bool ok = (half * 208 + nt * 16 + l15) < NK;
    #pragma unroll
    for (int q = 0; q < 4; ++q)
      acc[nt][q] = ok ? acc[nt][q] * SC : -1e30f;
  }
  float m_[4], s_[4];
  #pragma unroll
  for (int q = 0; q < 4; ++q) {
    float mm = acc[0][q];
    #pragma unroll
    for (int nt = 1; nt < 13; ++nt) mm = fmaxf(mm, acc[nt][q]);
    mm = fmaxf(mm, __shfl_xor(mm, 1));
    mm = fmaxf(mm, __shfl_xor(mm, 2));
    mm = fmaxf(mm, __shfl_xor(mm, 4));
    mm = fmaxf(mm, __shfl_xor(mm, 8));
    float ss = 0.f;
    #pragma unroll
    for (int nt = 0; nt < 13; ++nt) {
      const float e = exp2f((acc[nt][q] - mm) * L2E);
      acc[nt][q] = e;
      ss += e;
    }
    ss += __shfl_xor(ss, 1);
    ss += __shfl_xor(ss, 2);
    ss += __shfl_xor(ss, 4);
    ss += __shfl_xor(ss, 8);
    m_[q] = mm; s_[q] = ss;
  }
  // write per-half partials (lanes l15 0..3 carry q = l15)
  {
    const float mw = l15 == 0 ? m_[0] : l15 == 1 ? m_[1] : l15 == 2 ? m_[2] : m_[3];
    const float sw = l15 == 0 ? s_[0] : l15 == 1 ? s_[1] : l15 == 2 ? s_[2] : s_[3];
    if (l15 < 4) {
      const int pix = pg * 16 + l4 * 4 + l15;
      float2 v; v.x = mw; v.y = sw;
      *(float2*)(smem + XC_OFF + (half * 64 + pix) * 8) = v;
    }
  }
  __syncthreads();   // partials visible; all Q reads done

  // ---- combine halves; write normalized P (overlays Q region) ----
  float f_[4];
  #pragma unroll
  for (int q = 0; q < 4; ++q) {
    const int pix = pg * 16 + l4 * 4 + q;
    const float2 p0 = *(const float2*)(smem + XC_OFF + pix * 8);
    const float2 p1 = *(const float2*)(smem + XC_OFF + 512 + pix * 8);
    const float mt = fmaxf(p0.x, p1.x);
    const float st = p0.y * exp2f((p0.x - mt) * L2E) + p1.y * exp2f((p1.x - mt) * L2E);
    f_[q] = exp2f((m_[q] - mt) * L2E) / st;
  }
  #pragma unroll
  for (int nt = 0; nt < 13; ++nt) {
    #pragma unroll
    for (int q = 0; q < 4; ++q) {
      const int pix = pg * 16 + l4 * 4 + q;
      const int key = half * 208 + nt * 16 + l15;
      const int a = pix * P_STR + key * 2;
      *(u16*)(smem + (a ^ ((pix & 7) << 4))) = f2bf(acc[nt][q] * f_[q]);
    }
  }
  __syncthreads();   // P visible

  // ---- PV: wave (pg, chalf): 16 pix x 64 c; V-frags from global wsKT ----
  f32x4 acc2[4];
  #pragma unroll
  for (int ct = 0; ct < 4; ++ct) acc2[ct] = (f32x4){0.f, 0.f, 0.f, 0.f};
  {
    const u16* vbase = wsKTb + (size_t)(half * 64 + l15) * NKP + l4 * 8;
    #pragma unroll
    for (int kc = 0; kc < 13; ++kc) {
      const int pa = (pg * 16 + l15) * P_STR + kc * 64 + l4 * 16;
      const bf16x8 paf = *(const bf16x8*)(smem + (pa ^ ((l15 & 7) << 4)));
      #pragma unroll
      for (int ct = 0; ct < 4; ++ct) {
        const bf16x8 vf = *(const bf16x8*)(vbase + ct * 16 * NKP + kc * 32);
        acc2[ct] = __builtin_amdgcn_mfma_f32_16x16x32_bf16(paf, vf, acc2[ct], 0, 0, 0);
      }
    }
  }
  // ---- write AG [64 pix][128 c] bf16 ----
  #pragma unroll
  for (int ct = 0; ct < 4; ++ct) {
    #pragma unroll
    for (int q = 0; q < 4; ++q) {
      const int pix = pg * 16 + l4 * 4 + q;
      const int c = half * 64 + ct * 16 + l15;
      const int a = AG_OFF + pix * AG_STR + c * 2;
      *(u16*)(smem + (a ^ ((pix & 7) << 4))) = f2bf(acc2[ct][q]);
    }
  }
  __syncthreads();   // AG visible; P reads done

  // ---- conv: wave wv owns 16 o's; A=W frags (global), B=AG frags ----
  bf16x8 wf[4];
  #pragma unroll
  for (int kc = 0; kc < 4; ++kc) {
    const float* wr = W_out + (wv * 16 + l15) * C_N + kc * 32 + l4 * 8;
    const float4 w0 = *(const float4*)wr;
    const float4 w1 = *(const float4*)(wr + 4);
    bf16x8 t;
    t[0] = (short)f2bf(w0.x); t[1] = (short)f2bf(w0.y);
    t[2] = (short)f2bf(w0.z); t[3] = (short)f2bf(w0.w);
    t[4] = (short)f2bf(w1.x); t[5] = (short)f2bf(w1.y);
    t[6] = (short)f2bf(w1.z); t[7] = (short)f2bf(w1.w);
    wf[kc] = t;
  }
  float bias[4];
  #pragma unroll
  for (int q = 0; q < 4; ++q) bias[q] = b_out[wv * 16 + l4 * 4 + q];

  f32x4 acc3[4];
  #pragma unroll
  for (int pt = 0; pt < 4; ++pt) acc3[pt] = (f32x4){0.f, 0.f, 0.f, 0.f};
  #pragma unroll
  for (int kc = 0; kc < 4; ++kc) {
    #pragma unroll
    for (int pt = 0; pt < 4; ++pt) {
      const int pix = pt * 16 + l15;
      const int a = AG_OFF + pix * AG_STR + kc * 64 + l4 * 16;
      const bf16x8 agf = *(const bf16x8*)(smem + (a ^ ((pix & 7) << 4)));
      acc3[pt] = __builtin_amdgcn_mfma_f32_16x16x32_bf16(wf[kc], agf, acc3[pt], 0, 0, 0);
    }
  }
  // ---- conv D -> LDS f32 [128 o][64 pix] (overlays P region) ----
  #pragma unroll
  for (int pt = 0; pt < 4; ++pt) {
    #pragma unroll
    for (int q = 0; q < 4; ++q) {
      const int o = wv * 16 + l4 * 4 + q;
      const int pix = pt * 16 + l15;
      const int a = o * 256 + pix * 4;
      *(float*)(smem + (a ^ ((o & 7) << 4))) = acc3[pt][q] + bias[q];
    }
  }
  __syncthreads();

  // ---- coalesced store: + residual; 16 lanes = 256B contiguous per o-row ----
  #pragma unroll
  for (int it = 0; it < 4; ++it) {
    const int o = (tid >> 4) + it * 32;
    const int sub = tid & 15;
    const int a = o * 256 + sub * 16;
    const f32x4 v = *(const f32x4*)(smem + (a ^ ((o & 7) << 4)));
    const size_t gi = (((size_t)(b * C_N + o)) << 16) + pix0 + sub * 4;
    const float4 r = *(const float4*)(x5 + gi);
    float4 ov;
    ov.x = v[0] + r.x; ov.y = v[1] + r.y; ov.z = v[2] + r.z; ov.w = v[3] + r.w;
    *(float4*)(out + gi) = ov;
  }
}

extern "C" void kernel_launch(void* const* d_in, const int* in_sizes, int n_in,
                              void* d_out, int out_size, void* d_ws, size_t ws_size,
                              hipStream_t stream) {
  const float* x5    = (const float*)d_in[0];
  const float* W_out = (const float*)d_in[1];
  const float* b_out = (const float*)d_in[2];
  float* out = (float*)d_out;
  // ws: wsK [4][416][128] bf16 = 425984 B, wsKT [4][128][416] bf16 = 425984 B
  u16* wsK  = (u16*)d_ws;
  u16* wsKT = (u16*)((char*)d_ws + (size_t)B_N * NKP * C_N * 2);

  pool_kernel<<<512, 256, 0, stream>>>(x5, wsK, wsKT, out);

  hipFuncSetAttribute((const void*)attn_kernel,
                      hipFuncAttributeMaxDynamicSharedMemorySize, LDS_BYTES);
  attn_kernel<<<B_N * 1024, 512, LDS_BYTES, stream>>>(x5, wsK, wsKT, W_out, b_out, out);
}

// Round 6
// 318.803 us; speedup vs baseline: 9.6266x; 1.4750x over previous
//
#include <hip/hip_runtime.h>
#include <hip/hip_bf16.h>

typedef short bf16x8 __attribute__((ext_vector_type(8)));
typedef float f32x4  __attribute__((ext_vector_type(4)));
typedef unsigned short u16;

#define B_N 4
#define C_N 128
#define HW_ 256
#define NPIX 65536
#define NK 396
#define NKP 400
#define OUT_MAIN ((size_t)B_N * C_N * NPIX)
#define P12_OFF OUT_MAIN
#define P6_OFF  (P12_OFF + (size_t)B_N * C_N * 144)

#define VT_OFF 32768                  // VT region inside each 64KB buffer
#define P_OFF  131072                 // per-wave P/AGG region: 8 x 4096B
#define LDS_BYTES 163840              // 64K + 64K + 32K

static __device__ __forceinline__ u16 f2bf(float x) {
  __hip_bfloat16 h = __float2bfloat16(x);
  return *(u16*)&h;
}
static __device__ __forceinline__ unsigned pack2(float lo, float hi) {
  return ((unsigned)f2bf(hi) << 16) | f2bf(lo);
}
static __device__ __forceinline__ void gl_lds16(const void* g, void* l) {
  __builtin_amdgcn_global_load_lds(
      (const __attribute__((address_space(1))) unsigned*)g,
      (__attribute__((address_space(3))) unsigned*)l, 16, 0, 0);
}
#define MFMA32 __builtin_amdgcn_mfma_f32_16x16x32_bf16

// ---------------- kernel 1: multi-scale adaptive avg pools ----------------
__global__ __launch_bounds__(256) void pool_kernel(
    const float* __restrict__ x5, u16* __restrict__ wsK,
    u16* __restrict__ wsKT, float* __restrict__ out)
{
  __shared__ float yh[54][257];
  const int bc = blockIdx.x;          // b*128+c
  const int b  = bc >> 7;
  const int c  = bc & 127;
  const float* plane = x5 + (size_t)bc * NPIX;
  const int w = threadIdx.x;

  const int os_[7] = {16,12,9,7,6,3,1};
  const int ro_[7] = {0,16,28,37,44,50,53};
  float acc[7], acc2[7];
  int r_[7], e_[7], s2_[7];
  #pragma unroll
  for (int s = 0; s < 7; ++s) {
    acc[s] = 0.f; acc2[s] = 0.f; r_[s] = 0;
    e_[s]  = (HW_ + os_[s] - 1) / os_[s];
    s2_[s] = HW_ / os_[s];
  }
  #pragma unroll 4
  for (int h = 0; h < HW_; ++h) {
    const float v = plane[h * HW_ + w];
    #pragma unroll
    for (int s = 0; s < 7; ++s) {
      acc[s] += v;
      if (h >= s2_[s]) acc2[s] += v;
      if (h + 1 == e_[s]) {
        const int st = (r_[s] * HW_) / os_[s];
        yh[ro_[s] + r_[s]][w] = acc[s] * (1.0f / (float)(e_[s] - st));
        r_[s]++;
        acc[s] = acc2[s]; acc2[s] = 0.f;
        e_[s]  = ((r_[s] + 1) * HW_ + os_[s] - 1) / os_[s];
        s2_[s] = ((r_[s] + 1) * HW_) / os_[s];
      }
    }
  }
  __syncthreads();

  // zero key-padding 396..399
  if (threadIdx.x < NKP - NK) {
    wsK [((size_t)b * NKP + NK + threadIdx.x) * C_N + c] = 0;
    wsKT[(size_t)bc * NKP + NK + threadIdx.x] = 0;
  }

  for (int r = threadIdx.x; r < 576; r += 256) {
    int rr = r;
    int o, ro, kbase, dst;   // dst: 0=Key, 1=p12, 2=p6
    if      (rr < 256) { o = 16; ro = 0;  kbase = 140; dst = 0; }
    else if (rr < 400) { o = 12; ro = 16; kbase = 0;   dst = 1; rr -= 256; }
    else if (rr < 481) { o = 9;  ro = 28; kbase = 10;  dst = 0; rr -= 400; }
    else if (rr < 530) { o = 7;  ro = 37; kbase = 91;  dst = 0; rr -= 481; }
    else if (rr < 566) { o = 6;  ro = 44; kbase = 0;   dst = 2; rr -= 530; }
    else if (rr < 575) { o = 3;  ro = 50; kbase = 0;   dst = 0; rr -= 566; }
    else               { o = 1;  ro = 53; kbase = 9;   dst = 0; rr = 0;   }
    const int i = rr / o;
    const int j = rr - i * o;
    const int s = (j * HW_) / o;
    const int e = ((j + 1) * HW_ + o - 1) / o;
    float sum = 0.f;
    const float* row = yh[ro + i];
    for (int wq = s; wq < e; ++wq) sum += row[wq];
    const float v = sum * (1.0f / (float)(e - s));
    if (dst == 1) {
      out[P12_OFF + (size_t)bc * 144 + rr] = v;
    } else if (dst == 2) {
      out[P6_OFF + (size_t)bc * 36 + rr] = v;
    } else {
      const int key = kbase + rr;
      const u16 bv = f2bf(v);
      wsK [((size_t)b * NKP + key) * C_N + c] = bv;   // [b][key][c]
      wsKT[(size_t)bc * NKP + key]            = bv;   // [b][c][key]
    }
  }
}

// ---------------- attn staging helpers ----------------
template<int CB, int BUF>
static __device__ __forceinline__ void stage128(
    char* smem, const char* wsKb, const char* wsKTb, int wv, int lane)
{
  char* buf = smem + BUF * 65536;
  const int lr = lane >> 4, lc = lane & 15;
  #pragma unroll
  for (int j = 0; j < 4; ++j) {
    const int r0  = wv * 16 + j * 4;
    const int row = r0 + lr;
    gl_lds16(wsKb  + (size_t)(CB + row) * 256 + ((lc ^ (row & 15)) << 4),
             buf + r0 * 256);
    gl_lds16(wsKTb + (size_t)row * (NKP * 2) + CB * 2 + ((lc ^ (row & 15)) << 4),
             buf + VT_OFF + r0 * 256);
  }
}

template<int BUF>
static __device__ __forceinline__ void stage_tail(
    char* smem, const char* wsKb, const char* wsKTb, int wv, int lane)
{
  char* buf = smem + BUF * 65536;
  if (wv < 4) {               // K rows 0..15 = keys 384..399, 256B rows
    const int r0  = wv * 4;
    const int row = r0 + (lane >> 4);
    gl_lds16(wsKb + (size_t)(384 + row) * 256 + (((lane & 15) ^ (row & 15)) << 4),
             buf + r0 * 256);
  } else {                    // VT rows c: 64B each (32B real + 32B overread, zeroed later)
    #pragma unroll
    for (int j = 0; j < 2; ++j) {
      const int r0  = (wv - 4) * 32 + j * 16;
      const int row = r0 + (lane >> 2);
      gl_lds16(wsKTb + (size_t)row * (NKP * 2) + 768 + ((lane & 3) << 4),
               buf + VT_OFF + r0 * 64);
    }
  }
}

static __device__ __forceinline__ void stage_W(
    char* smem, const float* W_out, int wv, int lane)
{
  #pragma unroll
  for (int j = 0; j < 8; ++j) {
    const int r0  = (wv * 8 + j) * 2;
    const int row = r0 + (lane >> 5);
    gl_lds16((const char*)W_out + (size_t)row * 512 + (((lane & 31) ^ (row & 15)) << 4),
             smem + r0 * 512);
  }
}

// ---------------- per-64-key half: QK^T -> exp -> P(LDS) -> PV ----------------
template<int BUF, int HOFF, int TAIL>
static __device__ __forceinline__ void compute_half(
    char* smem, char* pbase, const bf16x8 (&qf)[2][4],
    f32x4 (&agg)[8][2], float (&d)[2], int l15, int l4)
{
  const char* buf = smem + BUF * 65536;
  constexpr int NT = TAIL ? 1 : 4;
  constexpr int KT = TAIL ? 1 : 2;
  const float SCL2 = 0.044194173824159216f * 1.4426950408889634f;

  f32x4 sA[NT][2];
  #pragma unroll
  for (int nt = 0; nt < NT; ++nt) {
    sA[nt][0] = (f32x4){0.f,0.f,0.f,0.f};
    sA[nt][1] = (f32x4){0.f,0.f,0.f,0.f};
  }
  #pragma unroll
  for (int nt = 0; nt < NT; ++nt) {
    bf16x8 kf[4];
    #pragma unroll
    for (int kc = 0; kc < 4; ++kc)
      kf[kc] = *(const bf16x8*)(buf + (HOFF + nt*16 + l15) * 256 +
                                ((kc*64 + l4*16) ^ (l15 << 4)));
    #pragma unroll
    for (int kc = 0; kc < 4; ++kc) {
      sA[nt][0] = MFMA32(kf[kc], qf[0][kc], sA[nt][0], 0, 0, 0);
      sA[nt][1] = MFMA32(kf[kc], qf[1][kc], sA[nt][1], 0, 0, 0);
    }
  }

  // exp (max-free) + store P to per-wave LDS [32 pix][64 keys], swizzled
  #pragma unroll
  for (int pt = 0; pt < 2; ++pt) {
    const int prow = pt * 16 + l15;
    const int sz = (prow & 7) << 4;
    #pragma unroll
    for (int nt = 0; nt < NT; ++nt) {
      float p[4];
      #pragma unroll
      for (int q = 0; q < 4; ++q) {
        float e = exp2f(sA[nt][pt][q] * SCL2);
        if (TAIL && (l4 * 4 + q >= 12)) e = 0.f;   // keys 396..399
        p[q] = e;
      }
      d[pt] += (p[0] + p[1]) + (p[2] + p[3]);
      uint2 pk;
      pk.x = pack2(p[0], p[1]);
      pk.y = pack2(p[2], p[3]);
      *(uint2*)(pbase + prow * 128 + ((nt*32 + l4*8) ^ sz)) = pk;
    }
    if (TAIL) {   // zero keys 16..31 so PV's b128 reads see zeros
      uint2 z; z.x = 0u; z.y = 0u;
      *(uint2*)(pbase + prow * 128 + ((32 + l4*8) ^ sz)) = z;
    }
  }
  asm volatile("s_waitcnt lgkmcnt(0)" ::: "memory");
  __builtin_amdgcn_sched_barrier(0);

  // PV: agg^T[c][pix] += V^T x P
  #pragma unroll
  for (int kt = 0; kt < KT; ++kt) {
    bf16x8 pf[2];
    #pragma unroll
    for (int pt = 0; pt < 2; ++pt) {
      const int prow = pt * 16 + l15;
      pf[pt] = *(const bf16x8*)(pbase + prow * 128 +
                                ((kt*64 + l4*16) ^ ((prow & 7) << 4)));
    }
    #pragma unroll
    for (int ct = 0; ct < 8; ++ct) {
      bf16x8 vf;
      if (TAIL)
        vf = *(const bf16x8*)(buf + VT_OFF + (ct*16 + l15) * 64 + l4*16);
      else
        vf = *(const bf16x8*)(buf + VT_OFF + (ct*16 + l15) * 256 +
                              ((HOFF*2 + kt*64 + l4*16) ^ (l15 << 4)));
      agg[ct][0] = MFMA32(vf, pf[0], agg[ct][0], 0, 0, 0);
      agg[ct][1] = MFMA32(vf, pf[1], agg[ct][1], 0, 0, 0);
    }
  }
}

// -------- kernel 2: MFMA attention + 1x1 conv + bias + residual --------
__global__ __launch_bounds__(512, 2) void attn_kernel(
    const float* __restrict__ x5, const u16* __restrict__ wsK,
    const u16* __restrict__ wsKT, const float* __restrict__ W_out,
    const float* __restrict__ b_out, float* __restrict__ out)
{
  extern __shared__ char smem[];
  const int tid  = threadIdx.x;
  const int b    = blockIdx.x >> 8;
  const int pix0 = (blockIdx.x & 255) << 8;
  const int lane = tid & 63, wv = tid >> 6;
  const int l15  = lane & 15, l4 = lane >> 4;
  char* pbase = smem + P_OFF + wv * 4096;

  const char* wsKb  = (const char*)wsK  + (size_t)b * NKP * C_N * 2;
  const char* wsKTb = (const char*)wsKT + (size_t)b * C_N * NKP * 2;

  stage128<0, 0>(smem, wsKb, wsKTb, wv, lane);

  // stage Q [256 pix][128 c] bf16 into buf1 (packed dwords, row-swizzled)
  {
    const float* r0p = x5 + (((size_t)(b * C_N + 2*lane)) << 16) + pix0 + wv * 32;
    const float* r1p = r0p + NPIX;
    float4 v0[8], v1[8];
    #pragma unroll
    for (int j = 0; j < 8; ++j) {
      v0[j] = *(const float4*)(r0p + j*4);
      v1[j] = *(const float4*)(r1p + j*4);
    }
    #pragma unroll
    for (int i = 0; i < 32; ++i) {
      const int pix = wv * 32 + i;
      const unsigned pk = pack2(((const float*)&v0[i>>2])[i&3],
                                ((const float*)&v1[i>>2])[i&3]);
      *(unsigned*)(smem + 65536 + pix * 256 + ((lane*4) ^ ((pix & 15) << 4))) = pk;
    }
  }
  asm volatile("s_waitcnt vmcnt(0)" ::: "memory");
  __syncthreads();

  bf16x8 qf[2][4];
  #pragma unroll
  for (int pt = 0; pt < 2; ++pt)
    #pragma unroll
    for (int kc = 0; kc < 4; ++kc)
      qf[pt][kc] = *(const bf16x8*)(smem + 65536 + (wv*32 + pt*16 + l15) * 256 +
                                    ((kc*64 + l4*16) ^ (l15 << 4)));
  __syncthreads();

  f32x4 agg[8][2];
  #pragma unroll
  for (int ct = 0; ct < 8; ++ct) {
    agg[ct][0] = (f32x4){0.f,0.f,0.f,0.f};
    agg[ct][1] = (f32x4){0.f,0.f,0.f,0.f};
  }
  float d[2] = {0.f, 0.f};

  stage128<128, 1>(smem, wsKb, wsKTb, wv, lane);
  compute_half<0, 0,  0>(smem, pbase, qf, agg, d, l15, l4);
  compute_half<0, 64, 0>(smem, pbase, qf, agg, d, l15, l4);
  asm volatile("s_waitcnt vmcnt(0)" ::: "memory");
  __syncthreads();

  stage128<256, 0>(smem, wsKb, wsKTb, wv, lane);
  compute_half<1, 0,  0>(smem, pbase, qf, agg, d, l15, l4);
  compute_half<1, 64, 0>(smem, pbase, qf, agg, d, l15, l4);
  asm volatile("s_waitcnt vmcnt(0)" ::: "memory");
  __syncthreads();

  stage_tail<1>(smem, wsKb, wsKTb, wv, lane);
  compute_half<0, 0,  0>(smem, pbase, qf, agg, d, l15, l4);
  compute_half<0, 64, 0>(smem, pbase, qf, agg, d, l15, l4);
  asm volatile("s_waitcnt vmcnt(0)" ::: "memory");
  __syncthreads();

  // zero VT tail pads (keys 400..415 slots) + stage W (f32) into buf0
  {
    uint2 z; z.x = 0u; z.y = 0u;
    *(uint2*)(smem + 65536 + VT_OFF + (tid >> 2) * 64 + 32 + (tid & 3) * 8) = z;
  }
  stage_W(smem, W_out, wv, lane);
  __syncthreads();   // drains lgkm (zeros) + vmcnt (W)

  compute_half<1, 0, 1>(smem, pbase, qf, agg, d, l15, l4);
  // everything below is per-wave; no more barriers needed

  // denominator over the 4 l4-groups sharing pixel l15
  float inv[2];
  #pragma unroll
  for (int pt = 0; pt < 2; ++pt) {
    float s = d[pt];
    s += __shfl_xor(s, 16);
    s += __shfl_xor(s, 32);
    inv[pt] = 1.0f / s;
  }

  // conv in two 64-c halves: AGG -> per-wave LDS -> mfma(W, AGG)
  f32x4 cacc[8][2];
  #pragma unroll
  for (int ot = 0; ot < 8; ++ot) {
    cacc[ot][0] = (f32x4){0.f,0.f,0.f,0.f};
    cacc[ot][1] = (f32x4){0.f,0.f,0.f,0.f};
  }
  #pragma unroll
  for (int h = 0; h < 2; ++h) {
    asm volatile("s_waitcnt lgkmcnt(0)" ::: "memory");   // h=1: reads of h=0 done
    __builtin_amdgcn_sched_barrier(0);
    #pragma unroll
    for (int pt = 0; pt < 2; ++pt) {
      const int prow = pt * 16 + l15;
      const int sz = (prow & 7) << 4;
      #pragma unroll
      for (int c4 = 0; c4 < 4; ++c4) {
        const f32x4 a = agg[h*4 + c4][pt];
        uint2 pk;
        pk.x = pack2(a[0] * inv[pt], a[1] * inv[pt]);
        pk.y = pack2(a[2] * inv[pt], a[3] * inv[pt]);
        *(uint2*)(pbase + prow * 128 + ((c4*32 + l4*8) ^ sz)) = pk;
      }
    }
    asm volatile("s_waitcnt lgkmcnt(0)" ::: "memory");
    __builtin_amdgcn_sched_barrier(0);

    bf16x8 agf[2][2];
    #pragma unroll
    for (int ck = 0; ck < 2; ++ck)
      #pragma unroll
      for (int pt = 0; pt < 2; ++pt) {
        const int prow = pt * 16 + l15;
        agf[ck][pt] = *(const bf16x8*)(pbase + prow * 128 +
                                       ((ck*64 + l4*16) ^ ((prow & 7) << 4)));
      }
    #pragma unroll
    for (int ot = 0; ot < 8; ++ot) {
      #pragma unroll
      for (int ck = 0; ck < 2; ++ck) {
        const int g0 = h*16 + ck*8 + l4*2;
        const f32x4 w0 = *(const f32x4*)(smem + (ot*16 + l15) * 512 + ((g0 ^ l15) << 4));
        const f32x4 w1 = *(const f32x4*)(smem + (ot*16 + l15) * 512 + (((g0+1) ^ l15) << 4));
        bf16x8 wa;
        wa[0] = (short)f2bf(w0[0]); wa[1] = (short)f2bf(w0[1]);
        wa[2] = (short)f2bf(w0[2]); wa[3] = (short)f2bf(w0[3]);
        wa[4] = (short)f2bf(w1[0]); wa[5] = (short)f2bf(w1[1]);
        wa[6] = (short)f2bf(w1[2]); wa[7] = (short)f2bf(w1[3]);
        cacc[ot][0] = MFMA32(wa, agf[ck][0], cacc[ot][0], 0, 0, 0);
        cacc[ot][1] = MFMA32(wa, agf[ck][1], cacc[ot][1], 0, 0, 0);
      }
    }
  }

  // store: + bias + residual
  #pragma unroll
  for (int ot = 0; ot < 8; ++ot) {
    const float4 bq = *(const float4*)(b_out + ot*16 + l4*4);
    #pragma unroll
    for (int pt = 0; pt < 2; ++pt) {
      #pragma unroll
      for (int q = 0; q < 4; ++q) {
        const int o = ot*16 + l4*4 + q;
        const size_t idx = (((size_t)(b * C_N + o)) << 16) + pix0 + wv*32 + pt*16 + l15;
        out[idx] = cacc[ot][pt][q] + ((const float*)&bq)[q] + x5[idx];
      }
    }
  }
}

extern "C" void kernel_launch(void* const* d_in, const int* in_sizes, int n_in,
                              void* d_out, int out_size, void* d_ws, size_t ws_size,
                              hipStream_t stream) {
  const float* x5    = (const float*)d_in[0];
  const float* W_out = (const float*)d_in[1];
  const float* b_out = (const float*)d_in[2];
  float* out = (float*)d_out;
  // ws layout: wsKT first (tail staging overreads 32B past a row; lands in wsK)
  u16* wsKT = (u16*)d_ws;                                        // [4][128][400] bf16
  u16* wsK  = (u16*)((char*)d_ws + (size_t)B_N * C_N * NKP * 2); // [4][400][128] bf16

  pool_kernel<<<512, 256, 0, stream>>>(x5, wsK, wsKT, out);

  hipFuncSetAttribute((const void*)attn_kernel,
                      hipFuncAttributeMaxDynamicSharedMemorySize, LDS_BYTES);
  attn_kernel<<<B_N * 256, 512, LDS_BYTES, stream>>>(x5, wsK, wsKT, W_out, b_out, out);
}

// Round 8
// 261.043 us; speedup vs baseline: 11.7567x; 1.2213x over previous
//
#include <hip/hip_runtime.h>
#include <hip/hip_bf16.h>

typedef short bf16x8 __attribute__((ext_vector_type(8)));
typedef float f32x4  __attribute__((ext_vector_type(4)));
typedef unsigned short u16;

#define B_N 4
#define C_N 128
#define HW_ 256
#define NPIX 65536
#define NK 396
#define NKP 400
#define OUT_MAIN ((size_t)B_N * C_N * NPIX)
#define P12_OFF OUT_MAIN
#define P6_OFF  (P12_OFF + (size_t)B_N * C_N * 144)

#define VT_OFF 32768                  // VT region inside each 64KB buffer
#define P_OFF  131072                 // per-wave P/AGG region: 8 x 4096B
#define LDS_BYTES 163840              // 64K + 64K + 32K

static __device__ __forceinline__ u16 f2bf(float x) {
  __hip_bfloat16 h = __float2bfloat16(x);
  return *(u16*)&h;
}
static __device__ __forceinline__ unsigned pack2(float lo, float hi) {
  return ((unsigned)f2bf(hi) << 16) | f2bf(lo);
}
static __device__ __forceinline__ void gl_lds16(const void* g, void* l) {
  __builtin_amdgcn_global_load_lds(
      (const __attribute__((address_space(1))) unsigned*)g,
      (__attribute__((address_space(3))) unsigned*)l, 16, 0, 0);
}
#define MFMA32 __builtin_amdgcn_mfma_f32_16x16x32_bf16

// ---------------- kernel 1: multi-scale adaptive avg pools ----------------
// 1024 thr = 128 col-pairs (float2) x 8 row-chunks of 32; per-chunk segment
// state machines; cross-chunk combine via LDS atomicAdd into yh[54][257].
__global__ __launch_bounds__(1024) void pool_kernel(
    const float* __restrict__ x5, u16* __restrict__ wsK,
    u16* __restrict__ wsKT, float* __restrict__ out)
{
  __shared__ float yh[54][257];
  const int tid = threadIdx.x;
  const int bc = blockIdx.x;          // b*128+c
  const int b  = bc >> 7;
  const int c  = bc & 127;
  const float2* plane2 = (const float2*)(x5 + (size_t)bc * NPIX);
  const int w2 = tid & 127;           // columns 2*w2, 2*w2+1
  const int q  = tid >> 7;            // row chunk 0..7
  const int h0 = q * 32;

  // zero the accumulator tile
  for (int i = tid; i < 54 * 257; i += 1024) ((float*)yh)[i] = 0.f;
  __syncthreads();

  const int os_[7] = {16,12,9,7,6,3,1};
  const int ro_[7] = {0,16,28,37,44,50,53};
  float ax[7], ay[7], a2x[7], a2y[7], inv_[7];
  int r_[7], e_[7], s2_[7];
  #pragma unroll
  for (int s = 0; s < 7; ++s) {
    const int o = os_[s];
    const int r = (h0 * o) >> 8;
    const int sr = (r * 256) / o;
    r_[s]  = r;
    e_[s]  = ((r + 1) * 256 + o - 1) / o;
    s2_[s] = ((r + 1) * 256) / o;
    inv_[s] = 1.0f / (float)(e_[s] - sr);
    ax[s] = 0.f; ay[s] = 0.f; a2x[s] = 0.f; a2y[s] = 0.f;
  }

  for (int h = h0; h < h0 + 32; ++h) {
    const float2 v = plane2[h * 128 + w2];
    #pragma unroll
    for (int s = 0; s < 7; ++s) {
      const int o = os_[s];
      ax[s] += v.x; ay[s] += v.y;
      if (h >= s2_[s]) { a2x[s] += v.x; a2y[s] += v.y; }
      if (h + 1 == e_[s]) {
        atomicAdd(&yh[ro_[s] + r_[s]][2*w2],     ax[s] * inv_[s]);
        atomicAdd(&yh[ro_[s] + r_[s]][2*w2 + 1], ay[s] * inv_[s]);
        r_[s]++;
        const int sr = s2_[s];
        e_[s]  = ((r_[s] + 1) * 256 + o - 1) / o;
        s2_[s] = ((r_[s] + 1) * 256) / o;
        inv_[s] = 1.0f / (float)(e_[s] - sr);
        ax[s] = a2x[s]; ay[s] = a2y[s];
        a2x[s] = 0.f; a2y[s] = 0.f;
      }
    }
  }
  // flush in-progress segments (partials for segments crossing chunk end)
  #pragma unroll
  for (int s = 0; s < 7; ++s) {
    const int o = os_[s];
    if (r_[s] < o) {
      atomicAdd(&yh[ro_[s] + r_[s]][2*w2],     ax[s] * inv_[s]);
      atomicAdd(&yh[ro_[s] + r_[s]][2*w2 + 1], ay[s] * inv_[s]);
      if (r_[s] + 1 < o && s2_[s] < h0 + 32) {
        const int sr2 = s2_[s];
        const int e2  = ((r_[s] + 2) * 256 + o - 1) / o;
        const float inv2 = 1.0f / (float)(e2 - sr2);
        atomicAdd(&yh[ro_[s] + r_[s] + 1][2*w2],     a2x[s] * inv2);
        atomicAdd(&yh[ro_[s] + r_[s] + 1][2*w2 + 1], a2y[s] * inv2);
      }
    }
  }
  __syncthreads();

  // zero key-padding 396..399
  if (tid < NKP - NK) {
    wsK [((size_t)b * NKP + NK + tid) * C_N + c] = 0;
    wsKT[(size_t)bc * NKP + NK + tid] = 0;
  }

  // Phase B: w-pool each yh row -> 576 outputs
  for (int r = tid; r < 576; r += 1024) {
    int rr = r;
    int o, ro, kbase, dst;   // dst: 0=Key, 1=p12, 2=p6
    if      (rr < 256) { o = 16; ro = 0;  kbase = 140; dst = 0; }
    else if (rr < 400) { o = 12; ro = 16; kbase = 0;   dst = 1; rr -= 256; }
    else if (rr < 481) { o = 9;  ro = 28; kbase = 10;  dst = 0; rr -= 400; }
    else if (rr < 530) { o = 7;  ro = 37; kbase = 91;  dst = 0; rr -= 481; }
    else if (rr < 566) { o = 6;  ro = 44; kbase = 0;   dst = 2; rr -= 530; }
    else if (rr < 575) { o = 3;  ro = 50; kbase = 0;   dst = 0; rr -= 566; }
    else               { o = 1;  ro = 53; kbase = 9;   dst = 0; rr = 0;   }
    const int i = rr / o;
    const int j = rr - i * o;
    const int s = (j * HW_) / o;
    const int e = ((j + 1) * HW_ + o - 1) / o;
    float sum = 0.f;
    const float* row = yh[ro + i];
    for (int wq = s; wq < e; ++wq) sum += row[wq];
    const float v = sum * (1.0f / (float)(e - s));
    if (dst == 1) {
      out[P12_OFF + (size_t)bc * 144 + rr] = v;
    } else if (dst == 2) {
      out[P6_OFF + (size_t)bc * 36 + rr] = v;
    } else {
      const int key = kbase + rr;
      const u16 bv = f2bf(v);
      wsK [((size_t)b * NKP + key) * C_N + c] = bv;   // [b][key][c]
      wsKT[(size_t)bc * NKP + key]            = bv;   // [b][c][key]
    }
  }
}

// ---------------- attn staging helpers ----------------
template<int CB, int BUF>
static __device__ __forceinline__ void stage128(
    char* smem, const char* wsKb, const char* wsKTb, int wv, int lane)
{
  char* buf = smem + BUF * 65536;
  const int lr = lane >> 4, lc = lane & 15;
  #pragma unroll
  for (int j = 0; j < 4; ++j) {
    const int r0  = wv * 16 + j * 4;
    const int row = r0 + lr;
    gl_lds16(wsKb  + (size_t)(CB + row) * 256 + ((lc ^ (row & 15)) << 4),
             buf + r0 * 256);
    gl_lds16(wsKTb + (size_t)row * (NKP * 2) + CB * 2 + ((lc ^ (row & 15)) << 4),
             buf + VT_OFF + r0 * 256);
  }
}

template<int BUF>
static __device__ __forceinline__ void stage_tail(
    char* smem, const char* wsKb, const char* wsKTb, int wv, int lane)
{
  char* buf = smem + BUF * 65536;
  if (wv < 4) {               // K rows 0..15 = keys 384..399, 256B rows
    const int r0  = wv * 4;
    const int row = r0 + (lane >> 4);
    gl_lds16(wsKb + (size_t)(384 + row) * 256 + (((lane & 15) ^ (row & 15)) << 4),
             buf + r0 * 256);
  } else {                    // VT rows c: 64B each (32B real + 32B overread, zeroed later)
    #pragma unroll
    for (int j = 0; j < 2; ++j) {
      const int r0  = (wv - 4) * 32 + j * 16;
      const int row = r0 + (lane >> 2);
      gl_lds16(wsKTb + (size_t)row * (NKP * 2) + 768 + ((lane & 3) << 4),
               buf + VT_OFF + r0 * 64);
    }
  }
}

static __device__ __forceinline__ void stage_W(
    char* smem, const float* W_out, int wv, int lane)
{
  #pragma unroll
  for (int j = 0; j < 8; ++j) {
    const int r0  = (wv * 8 + j) * 2;
    const int row = r0 + (lane >> 5);
    gl_lds16((const char*)W_out + (size_t)row * 512 + (((lane & 31) ^ (row & 15)) << 4),
             smem + r0 * 512);
  }
}

// ---------------- per-64-key half: QK^T -> exp -> P(LDS) -> PV ----------------
template<int BUF, int HOFF, int TAIL>
static __device__ __forceinline__ void compute_half(
    char* smem, char* pbase, const bf16x8 (&qf)[2][4],
    f32x4 (&agg)[8][2], float (&d)[2], int l15, int l4)
{
  const char* buf = smem + BUF * 65536;
  constexpr int NT = TAIL ? 1 : 4;
  constexpr int KT = TAIL ? 1 : 2;
  const float SCL2 = 0.044194173824159216f * 1.4426950408889634f;

  f32x4 sA[NT][2];
  #pragma unroll
  for (int nt = 0; nt < NT; ++nt) {
    sA[nt][0] = (f32x4){0.f,0.f,0.f,0.f};
    sA[nt][1] = (f32x4){0.f,0.f,0.f,0.f};
  }
  #pragma unroll
  for (int nt = 0; nt < NT; ++nt) {
    bf16x8 kf[4];
    #pragma unroll
    for (int kc = 0; kc < 4; ++kc)
      kf[kc] = *(const bf16x8*)(buf + (HOFF + nt*16 + l15) * 256 +
                                ((kc*64 + l4*16) ^ (l15 << 4)));
    #pragma unroll
    for (int kc = 0; kc < 4; ++kc) {
      sA[nt][0] = MFMA32(kf[kc], qf[0][kc], sA[nt][0], 0, 0, 0);
      sA[nt][1] = MFMA32(kf[kc], qf[1][kc], sA[nt][1], 0, 0, 0);
    }
  }

  // exp (max-free) + store P to per-wave LDS [32 pix][64 keys], swizzled
  #pragma unroll
  for (int pt = 0; pt < 2; ++pt) {
    const int prow = pt * 16 + l15;
    const int sz = (prow & 7) << 4;
    #pragma unroll
    for (int nt = 0; nt < NT; ++nt) {
      float p[4];
      #pragma unroll
      for (int q = 0; q < 4; ++q) {
        float e = exp2f(sA[nt][pt][q] * SCL2);
        if (TAIL && (l4 * 4 + q >= 12)) e = 0.f;   // keys 396..399
        p[q] = e;
      }
      d[pt] += (p[0] + p[1]) + (p[2] + p[3]);
      uint2 pk;
      pk.x = pack2(p[0], p[1]);
      pk.y = pack2(p[2], p[3]);
      *(uint2*)(pbase + prow * 128 + ((nt*32 + l4*8) ^ sz)) = pk;
    }
    if (TAIL) {   // zero keys 16..31 so PV's b128 reads see zeros
      uint2 z; z.x = 0u; z.y = 0u;
      *(uint2*)(pbase + prow * 128 + ((32 + l4*8) ^ sz)) = z;
    }
  }
  asm volatile("s_waitcnt lgkmcnt(0)" ::: "memory");
  __builtin_amdgcn_sched_barrier(0);

  // PV: agg^T[c][pix] += V^T x P
  #pragma unroll
  for (int kt = 0; kt < KT; ++kt) {
    bf16x8 pf[2];
    #pragma unroll
    for (int pt = 0; pt < 2; ++pt) {
      const int prow = pt * 16 + l15;
      pf[pt] = *(const bf16x8*)(pbase + prow * 128 +
                                ((kt*64 + l4*16) ^ ((prow & 7) << 4)));
    }
    #pragma unroll
    for (int ct = 0; ct < 8; ++ct) {
      bf16x8 vf;
      if (TAIL)
        vf = *(const bf16x8*)(buf + VT_OFF + (ct*16 + l15) * 64 + l4*16);
      else
        vf = *(const bf16x8*)(buf + VT_OFF + (ct*16 + l15) * 256 +
                              ((HOFF*2 + kt*64 + l4*16) ^ (l15 << 4)));
      agg[ct][0] = MFMA32(vf, pf[0], agg[ct][0], 0, 0, 0);
      agg[ct][1] = MFMA32(vf, pf[1], agg[ct][1], 0, 0, 0);
    }
  }
}

// -------- kernel 2: MFMA attention + 1x1 conv + bias + residual --------
__global__ __launch_bounds__(512, 2) void attn_kernel(
    const float* __restrict__ x5, const u16* __restrict__ wsK,
    const u16* __restrict__ wsKT, const float* __restrict__ W_out,
    const float* __restrict__ b_out, float* __restrict__ out)
{
  extern __shared__ char smem[];
  const int tid  = threadIdx.x;
  const int b    = blockIdx.x >> 8;
  const int pix0 = (blockIdx.x & 255) << 8;
  const int lane = tid & 63, wv = tid >> 6;
  const int l15  = lane & 15, l4 = lane >> 4;
  char* pbase = smem + P_OFF + wv * 4096;

  const char* wsKb  = (const char*)wsK  + (size_t)b * NKP * C_N * 2;
  const char* wsKTb = (const char*)wsKT + (size_t)b * C_N * NKP * 2;

  stage128<0, 0>(smem, wsKb, wsKTb, wv, lane);

  // stage Q [256 pix][128 c] bf16 into buf1 (packed dwords, row-swizzled)
  {
    const float* r0p = x5 + (((size_t)(b * C_N + 2*lane)) << 16) + pix0 + wv * 32;
    const float* r1p = r0p + NPIX;
    float4 v0[8], v1[8];
    #pragma unroll
    for (int j = 0; j < 8; ++j) {
      v0[j] = *(const float4*)(r0p + j*4);
      v1[j] = *(const float4*)(r1p + j*4);
    }
    #pragma unroll
    for (int i = 0; i < 32; ++i) {
      const int pix = wv * 32 + i;
      const unsigned pk = pack2(((const float*)&v0[i>>2])[i&3],
                                ((const float*)&v1[i>>2])[i&3]);
      *(unsigned*)(smem + 65536 + pix * 256 + ((lane*4) ^ ((pix & 15) << 4))) = pk;
    }
  }
  asm volatile("s_waitcnt vmcnt(0)" ::: "memory");
  __syncthreads();

  bf16x8 qf[2][4];
  #pragma unroll
  for (int pt = 0; pt < 2; ++pt)
    #pragma unroll
    for (int kc = 0; kc < 4; ++kc)
      qf[pt][kc] = *(const bf16x8*)(smem + 65536 + (wv*32 + pt*16 + l15) * 256 +
                                    ((kc*64 + l4*16) ^ (l15 << 4)));
  __syncthreads();

  f32x4 agg[8][2];
  #pragma unroll
  for (int ct = 0; ct < 8; ++ct) {
    agg[ct][0] = (f32x4){0.f,0.f,0.f,0.f};
    agg[ct][1] = (f32x4){0.f,0.f,0.f,0.f};
  }
  float d[2] = {0.f, 0.f};

  stage128<128, 1>(smem, wsKb, wsKTb, wv, lane);
  compute_half<0, 0,  0>(smem, pbase, qf, agg, d, l15, l4);
  compute_half<0, 64, 0>(smem, pbase, qf, agg, d, l15, l4);
  asm volatile("s_waitcnt vmcnt(0)" ::: "memory");
  __syncthreads();

  stage128<256, 0>(smem, wsKb, wsKTb, wv, lane);
  compute_half<1, 0,  0>(smem, pbase, qf, agg, d, l15, l4);
  compute_half<1, 64, 0>(smem, pbase, qf, agg, d, l15, l4);
  asm volatile("s_waitcnt vmcnt(0)" ::: "memory");
  __syncthreads();

  stage_tail<1>(smem, wsKb, wsKTb, wv, lane);
  compute_half<0, 0,  0>(smem, pbase, qf, agg, d, l15, l4);
  compute_half<0, 64, 0>(smem, pbase, qf, agg, d, l15, l4);
  asm volatile("s_waitcnt vmcnt(0)" ::: "memory");
  __syncthreads();

  // zero VT tail pads (keys 400..415 slots) + stage W (f32) into buf0
  {
    uint2 z; z.x = 0u; z.y = 0u;
    *(uint2*)(smem + 65536 + VT_OFF + (tid >> 2) * 64 + 32 + (tid & 3) * 8) = z;
  }
  stage_W(smem, W_out, wv, lane);
  __syncthreads();   // drains lgkm (zeros) + vmcnt (W)

  compute_half<1, 0, 1>(smem, pbase, qf, agg, d, l15, l4);
  // everything below is per-wave; no more barriers needed

  // denominator over the 4 l4-groups sharing pixel l15
  float inv[2];
  #pragma unroll
  for (int pt = 0; pt < 2; ++pt) {
    float s = d[pt];
    s += __shfl_xor(s, 16);
    s += __shfl_xor(s, 32);
    inv[pt] = 1.0f / s;
  }

  // conv in two 64-c halves: AGG -> per-wave LDS -> mfma(W, AGG)
  f32x4 cacc[8][2];
  #pragma unroll
  for (int ot = 0; ot < 8; ++ot) {
    cacc[ot][0] = (f32x4){0.f,0.f,0.f,0.f};
    cacc[ot][1] = (f32x4){0.f,0.f,0.f,0.f};
  }
  #pragma unroll
  for (int h = 0; h < 2; ++h) {
    asm volatile("s_waitcnt lgkmcnt(0)" ::: "memory");   // h=1: reads of h=0 done
    __builtin_amdgcn_sched_barrier(0);
    #pragma unroll
    for (int pt = 0; pt < 2; ++pt) {
      const int prow = pt * 16 + l15;
      const int sz = (prow & 7) << 4;
      #pragma unroll
      for (int c4 = 0; c4 < 4; ++c4) {
        const f32x4 a = agg[h*4 + c4][pt];
        uint2 pk;
        pk.x = pack2(a[0] * inv[pt], a[1] * inv[pt]);
        pk.y = pack2(a[2] * inv[pt], a[3] * inv[pt]);
        *(uint2*)(pbase + prow * 128 + ((c4*32 + l4*8) ^ sz)) = pk;
      }
    }
    asm volatile("s_waitcnt lgkmcnt(0)" ::: "memory");
    __builtin_amdgcn_sched_barrier(0);

    bf16x8 agf[2][2];
    #pragma unroll
    for (int ck = 0; ck < 2; ++ck)
      #pragma unroll
      for (int pt = 0; pt < 2; ++pt) {
        const int prow = pt * 16 + l15;
        agf[ck][pt] = *(const bf16x8*)(pbase + prow * 128 +
                                       ((ck*64 + l4*16) ^ ((prow & 7) << 4)));
      }
    #pragma unroll
    for (int ot = 0; ot < 8; ++ot) {
      #pragma unroll
      for (int ck = 0; ck < 2; ++ck) {
        const int g0 = h*16 + ck*8 + l4*2;
        const f32x4 w0 = *(const f32x4*)(smem + (ot*16 + l15) * 512 + ((g0 ^ l15) << 4));
        const f32x4 w1 = *(const f32x4*)(smem + (ot*16 + l15) * 512 + (((g0+1) ^ l15) << 4));
        bf16x8 wa;
        wa[0] = (short)f2bf(w0[0]); wa[1] = (short)f2bf(w0[1]);
        wa[2] = (short)f2bf(w0[2]); wa[3] = (short)f2bf(w0[3]);
        wa[4] = (short)f2bf(w1[0]); wa[5] = (short)f2bf(w1[1]);
        wa[6] = (short)f2bf(w1[2]); wa[7] = (short)f2bf(w1[3]);
        cacc[ot][0] = MFMA32(wa, agf[ck][0], cacc[ot][0], 0, 0, 0);
        cacc[ot][1] = MFMA32(wa, agf[ck][1], cacc[ot][1], 0, 0, 0);
      }
    }
  }

  // store: + bias + residual
  #pragma unroll
  for (int ot = 0; ot < 8; ++ot) {
    const float4 bq = *(const float4*)(b_out + ot*16 + l4*4);
    #pragma unroll
    for (int pt = 0; pt < 2; ++pt) {
      #pragma unroll
      for (int q = 0; q < 4; ++q) {
        const int o = ot*16 + l4*4 + q;
        const size_t idx = (((size_t)(b * C_N + o)) << 16) + pix0 + wv*32 + pt*16 + l15;
        out[idx] = cacc[ot][pt][q] + ((const float*)&bq)[q] + x5[idx];
      }
    }
  }
}

extern "C" void kernel_launch(void* const* d_in, const int* in_sizes, int n_in,
                              void* d_out, int out_size, void* d_ws, size_t ws_size,
                              hipStream_t stream) {
  const float* x5    = (const float*)d_in[0];
  const float* W_out = (const float*)d_in[1];
  const float* b_out = (const float*)d_in[2];
  float* out = (float*)d_out;
  // ws layout: wsKT first (tail staging overreads 32B past a row; lands in wsK)
  u16* wsKT = (u16*)d_ws;                                        // [4][128][400] bf16
  u16* wsK  = (u16*)((char*)d_ws + (size_t)B_N * C_N * NKP * 2); // [4][400][128] bf16

  pool_kernel<<<512, 1024, 0, stream>>>(x5, wsK, wsKT, out);

  hipFuncSetAttribute((const void*)attn_kernel,
                      hipFuncAttributeMaxDynamicSharedMemorySize, LDS_BYTES);
  attn_kernel<<<B_N * 256, 512, LDS_BYTES, stream>>>(x5, wsK, wsKT, W_out, b_out, out);
}

// Round 9
// 213.126 us; speedup vs baseline: 14.3999x; 1.2248x over previous
//
#include <hip/hip_runtime.h>
#include <hip/hip_bf16.h>

typedef short bf16x8 __attribute__((ext_vector_type(8)));
typedef float f32x4  __attribute__((ext_vector_type(4)));
typedef unsigned short u16;

#define B_N 4
#define C_N 128
#define HW_ 256
#define NPIX 65536
#define NK 396
#define NKP 400
#define OUT_MAIN ((size_t)B_N * C_N * NPIX)
#define P12_OFF OUT_MAIN
#define P6_OFF  (P12_OFF + (size_t)B_N * C_N * 144)

// attn LDS arena: two 32KB buffers (K 16KB + VT 16KB each) + per-wave P 2KB x4
#define BUFSZ  32768
#define VT_OFF 16384
#define P_OFF  65536
#define LDS_BYTES 73728

static __device__ __forceinline__ u16 f2bf(float x) {
  __hip_bfloat16 h = __float2bfloat16(x);
  return *(u16*)&h;
}
static __device__ __forceinline__ unsigned pack2(float lo, float hi) {
  return ((unsigned)f2bf(hi) << 16) | f2bf(lo);
}
static __device__ __forceinline__ void gl_lds16(const void* g, void* l) {
  __builtin_amdgcn_global_load_lds(
      (const __attribute__((address_space(1))) unsigned*)g,
      (__attribute__((address_space(3))) unsigned*)l, 16, 0, 0);
}
#define MFMA32 __builtin_amdgcn_mfma_f32_16x16x32_bf16
#define LGKM0 do { asm volatile("s_waitcnt lgkmcnt(0)" ::: "memory"); \
                   __builtin_amdgcn_sched_barrier(0); } while (0)

// ---------------- kernel 1: multi-scale adaptive avg pools ----------------
// 1024 thr = 128 col-pairs (float2) x 8 row-chunks of 32; per-chunk segment
// state machines; cross-chunk combine via LDS atomicAdd into yh[54][257].
// Blocks 0..15 additionally convert W_out f32 -> wsW bf16 (for attn staging).
__global__ __launch_bounds__(1024) void pool_kernel(
    const float* __restrict__ x5, const float* __restrict__ W_out,
    u16* __restrict__ wsK, u16* __restrict__ wsKT, u16* __restrict__ wsW,
    float* __restrict__ out)
{
  __shared__ float yh[54][257];
  const int tid = threadIdx.x;
  const int bc = blockIdx.x;          // b*128+c
  const int b  = bc >> 7;
  const int c  = bc & 127;
  const float2* plane2 = (const float2*)(x5 + (size_t)bc * NPIX);
  const int w2 = tid & 127;           // columns 2*w2, 2*w2+1
  const int q  = tid >> 7;            // row chunk 0..7
  const int h0 = q * 32;

  if (bc < 16) {                      // W f32 -> bf16 once
    const int idx = bc * 1024 + tid;
    wsW[idx] = f2bf(W_out[idx]);
  }

  // zero the accumulator tile
  for (int i = tid; i < 54 * 257; i += 1024) ((float*)yh)[i] = 0.f;
  __syncthreads();

  const int os_[7] = {16,12,9,7,6,3,1};
  const int ro_[7] = {0,16,28,37,44,50,53};
  float ax[7], ay[7], a2x[7], a2y[7], inv_[7];
  int r_[7], e_[7], s2_[7];
  #pragma unroll
  for (int s = 0; s < 7; ++s) {
    const int o = os_[s];
    const int r = (h0 * o) >> 8;
    const int sr = (r * 256) / o;
    r_[s]  = r;
    e_[s]  = ((r + 1) * 256 + o - 1) / o;
    s2_[s] = ((r + 1) * 256) / o;
    inv_[s] = 1.0f / (float)(e_[s] - sr);
    ax[s] = 0.f; ay[s] = 0.f; a2x[s] = 0.f; a2y[s] = 0.f;
  }

  for (int h = h0; h < h0 + 32; ++h) {
    const float2 v = plane2[h * 128 + w2];
    #pragma unroll
    for (int s = 0; s < 7; ++s) {
      const int o = os_[s];
      ax[s] += v.x; ay[s] += v.y;
      if (h >= s2_[s]) { a2x[s] += v.x; a2y[s] += v.y; }
      if (h + 1 == e_[s]) {
        atomicAdd(&yh[ro_[s] + r_[s]][2*w2],     ax[s] * inv_[s]);
        atomicAdd(&yh[ro_[s] + r_[s]][2*w2 + 1], ay[s] * inv_[s]);
        r_[s]++;
        const int sr = s2_[s];
        e_[s]  = ((r_[s] + 1) * 256 + o - 1) / o;
        s2_[s] = ((r_[s] + 1) * 256) / o;
        inv_[s] = 1.0f / (float)(e_[s] - sr);
        ax[s] = a2x[s]; ay[s] = a2y[s];
        a2x[s] = 0.f; a2y[s] = 0.f;
      }
    }
  }
  // flush in-progress segments (partials for segments crossing chunk end)
  #pragma unroll
  for (int s = 0; s < 7; ++s) {
    const int o = os_[s];
    if (r_[s] < o) {
      atomicAdd(&yh[ro_[s] + r_[s]][2*w2],     ax[s] * inv_[s]);
      atomicAdd(&yh[ro_[s] + r_[s]][2*w2 + 1], ay[s] * inv_[s]);
      if (r_[s] + 1 < o && s2_[s] < h0 + 32) {
        const int sr2 = s2_[s];
        const int e2  = ((r_[s] + 2) * 256 + o - 1) / o;
        const float inv2 = 1.0f / (float)(e2 - sr2);
        atomicAdd(&yh[ro_[s] + r_[s] + 1][2*w2],     a2x[s] * inv2);
        atomicAdd(&yh[ro_[s] + r_[s] + 1][2*w2 + 1], a2y[s] * inv2);
      }
    }
  }
  __syncthreads();

  // zero key-padding 396..399
  if (tid < NKP - NK) {
    wsK [((size_t)b * NKP + NK + tid) * C_N + c] = 0;
    wsKT[(size_t)bc * NKP + NK + tid] = 0;
  }

  // Phase B: w-pool each yh row -> 576 outputs
  for (int r = tid; r < 576; r += 1024) {
    int rr = r;
    int o, ro, kbase, dst;   // dst: 0=Key, 1=p12, 2=p6
    if      (rr < 256) { o = 16; ro = 0;  kbase = 140; dst = 0; }
    else if (rr < 400) { o = 12; ro = 16; kbase = 0;   dst = 1; rr -= 256; }
    else if (rr < 481) { o = 9;  ro = 28; kbase = 10;  dst = 0; rr -= 400; }
    else if (rr < 530) { o = 7;  ro = 37; kbase = 91;  dst = 0; rr -= 481; }
    else if (rr < 566) { o = 6;  ro = 44; kbase = 0;   dst = 2; rr -= 530; }
    else if (rr < 575) { o = 3;  ro = 50; kbase = 0;   dst = 0; rr -= 566; }
    else               { o = 1;  ro = 53; kbase = 9;   dst = 0; rr = 0;   }
    const int i = rr / o;
    const int j = rr - i * o;
    const int s = (j * HW_) / o;
    const int e = ((j + 1) * HW_ + o - 1) / o;
    float sum = 0.f;
    const float* row = yh[ro + i];
    for (int wq = s; wq < e; ++wq) sum += row[wq];
    const float v = sum * (1.0f / (float)(e - s));
    if (dst == 1) {
      out[P12_OFF + (size_t)bc * 144 + rr] = v;
    } else if (dst == 2) {
      out[P6_OFF + (size_t)bc * 36 + rr] = v;
    } else {
      const int key = kbase + rr;
      const u16 bv = f2bf(v);
      wsK [((size_t)b * NKP + key) * C_N + c] = bv;   // [b][key][c]
      wsKT[(size_t)bc * NKP + key]            = bv;   // [b][c][key]
    }
  }
}

// ---------------- attn staging helpers (256 threads = 4 waves) ------------
template<int CB, int BUF>
static __device__ __forceinline__ void stage64(
    char* smem, const char* wsKb, const char* wsKTb, int wv, int lane)
{
  char* buf = smem + BUF * BUFSZ;
  #pragma unroll
  for (int j = 0; j < 4; ++j) {
    const int krow = CB + j*16 + wv*4 + (lane >> 4);      // 64 key rows x 256B
    gl_lds16(wsKb + (size_t)krow * 256 + (((lane & 15) ^ (krow & 15)) << 4),
             buf + j*4096 + wv*1024);
    const int vrow = j*32 + wv*8 + (lane >> 3);           // 128 c rows x 128B
    gl_lds16(wsKTb + (size_t)vrow * (NKP*2) + CB*2 + (((lane & 7) ^ (vrow & 7)) << 4),
             buf + VT_OFF + j*4096 + wv*1024);
  }
}

static __device__ __forceinline__ void stage_tail(
    char* buf, const char* wsKb, const char* wsKTb, int wv, int lane)
{
  {  // K: 16 rows (keys 384..399) x 256B
    const int row = wv*4 + (lane >> 4);
    gl_lds16(wsKb + (size_t)(384 + row) * 256 + (((lane & 15) ^ (row & 15)) << 4),
             buf + wv * 1024);
  }
  #pragma unroll
  for (int j = 0; j < 2; ++j) {  // VT: 128 rows x 64B (32B real + 32B overread)
    const int row = j*64 + wv*16 + (lane >> 2);
    gl_lds16(wsKTb + (size_t)row * (NKP*2) + 768 + ((lane & 3) << 4),
             buf + VT_OFF + j*4096 + wv*1024);
  }
}

static __device__ __forceinline__ void stage_W(
    char* smem, const u16* wsW, int wv, int lane)
{
  #pragma unroll
  for (int j = 0; j < 8; ++j) {   // 128 rows x 256B bf16 -> buf1
    const int row = j*16 + wv*4 + (lane >> 4);
    gl_lds16((const char*)wsW + (size_t)row * 256 + (((lane & 15) ^ (row & 15)) << 4),
             smem + BUFSZ + j*4096 + wv*1024);
  }
}

// ---------------- per-64-key chunk: QK^T -> exp -> P(LDS) -> PV -----------
template<int BUF, int TAIL>
static __device__ __forceinline__ void compute64(
    char* smem, char* pbase, const bf16x8 (&qf)[2][4],
    f32x4 (&agg)[8][2], float (&d)[2], int l15, int l4)
{
  const char* buf = smem + BUF * BUFSZ;
  constexpr int NT   = TAIL ? 1 : 4;
  constexpr int SUBS = TAIL ? 1 : 2;
  const float SCL2 = 0.044194173824159216f * 1.4426950408889634f;

  f32x4 sA[NT][2];
  #pragma unroll
  for (int nt = 0; nt < NT; ++nt) {
    sA[nt][0] = (f32x4){0.f,0.f,0.f,0.f};
    sA[nt][1] = (f32x4){0.f,0.f,0.f,0.f};
  }
  #pragma unroll
  for (int nt = 0; nt < NT; ++nt) {
    bf16x8 kf[4];
    #pragma unroll
    for (int kc = 0; kc < 4; ++kc)
      kf[kc] = *(const bf16x8*)(buf + (nt*16 + l15) * 256 +
                                ((kc*64 + l4*16) ^ (l15 << 4)));
    #pragma unroll
    for (int kc = 0; kc < 4; ++kc) {
      sA[nt][0] = MFMA32(kf[kc], qf[0][kc], sA[nt][0], 0, 0, 0);
      sA[nt][1] = MFMA32(kf[kc], qf[1][kc], sA[nt][1], 0, 0, 0);
    }
  }

  #pragma unroll
  for (int sub = 0; sub < SUBS; ++sub) {
    if (sub) LGKM0;                      // prior sub's P reads drained
    #pragma unroll
    for (int pt = 0; pt < 2; ++pt) {
      const int prow = pt*16 + l15;
      const int sz2  = (prow & 3) << 4;
      #pragma unroll
      for (int u = 0; u < (TAIL ? 1 : 2); ++u) {
        const int nt = sub*2 + u;
        float p[4];
        #pragma unroll
        for (int qi = 0; qi < 4; ++qi) {
          float e = exp2f(sA[nt][pt][qi] * SCL2);
          if (TAIL && (l4*4 + qi >= 12)) e = 0.f;   // keys 396..399
          p[qi] = e;
        }
        d[pt] += (p[0] + p[1]) + (p[2] + p[3]);
        uint2 pk;
        pk.x = pack2(p[0], p[1]);
        pk.y = pack2(p[2], p[3]);
        *(uint2*)(pbase + prow*64 + ((u*32 + l4*8) ^ sz2)) = pk;
      }
      if (TAIL) {   // zero local keys 16..31 so pf b128 reads see zeros
        uint2 z; z.x = 0u; z.y = 0u;
        *(uint2*)(pbase + prow*64 + ((32 + l4*8) ^ sz2)) = z;
      }
    }
    LGKM0;

    bf16x8 pf[2];
    #pragma unroll
    for (int pt = 0; pt < 2; ++pt) {
      const int prow = pt*16 + l15;
      pf[pt] = *(const bf16x8*)(pbase + prow*64 + ((l4*16) ^ ((prow & 3) << 4)));
    }
    #pragma unroll
    for (int ct = 0; ct < 8; ++ct) {
      const int vrow = ct*16 + l15;
      bf16x8 vf;
      if (TAIL)
        vf = *(const bf16x8*)(buf + VT_OFF + vrow*64 + l4*16);
      else
        vf = *(const bf16x8*)(buf + VT_OFF + vrow*128 +
                              ((sub*64 + l4*16) ^ ((vrow & 7) << 4)));
      agg[ct][0] = MFMA32(vf, pf[0], agg[ct][0], 0, 0, 0);
      agg[ct][1] = MFMA32(vf, pf[1], agg[ct][1], 0, 0, 0);
    }
  }
}

// -------- kernel 2: MFMA attention + 1x1 conv + bias + residual --------
__global__ __launch_bounds__(256, 2) void attn_kernel(
    const float* __restrict__ x5, const u16* __restrict__ wsK,
    const u16* __restrict__ wsKT, const u16* __restrict__ wsW,
    const float* __restrict__ b_out, float* __restrict__ out)
{
  extern __shared__ char smem[];
  const int tid  = threadIdx.x;
  const int b    = blockIdx.x >> 9;
  const int pix0 = (blockIdx.x & 511) << 7;
  const int lane = tid & 63, wv = tid >> 6;
  const int l15  = lane & 15, l4 = lane >> 4;
  char* pbase = smem + P_OFF + wv * 2048;

  const char* wsKb  = (const char*)wsK  + (size_t)b * NKP * C_N * 2;
  const char* wsKTb = (const char*)wsKT + (size_t)b * C_N * NKP * 2;

  // ---- stage Q [128 pix][128 c] bf16 into buf0 (row-swizzled) ----
  {
    const float* r0p = x5 + (((size_t)(b * C_N + 2*lane)) << 16) + pix0 + wv * 32;
    const float* r1p = r0p + NPIX;
    float4 v0[8], v1[8];
    #pragma unroll
    for (int j = 0; j < 8; ++j) {
      v0[j] = *(const float4*)(r0p + j*4);
      v1[j] = *(const float4*)(r1p + j*4);
    }
    #pragma unroll
    for (int i = 0; i < 32; ++i) {
      const int pix = wv * 32 + i;
      const unsigned pk = pack2(((const float*)&v0[i>>2])[i&3],
                                ((const float*)&v1[i>>2])[i&3]);
      *(unsigned*)(smem + pix * 256 + ((lane*4) ^ ((pix & 15) << 4))) = pk;
    }
  }
  __syncthreads();

  bf16x8 qf[2][4];
  #pragma unroll
  for (int pt = 0; pt < 2; ++pt)
    #pragma unroll
    for (int kc = 0; kc < 4; ++kc)
      qf[pt][kc] = *(const bf16x8*)(smem + (wv*32 + pt*16 + l15) * 256 +
                                    ((kc*64 + l4*16) ^ (l15 << 4)));
  __syncthreads();

  f32x4 agg[8][2];
  #pragma unroll
  for (int ct = 0; ct < 8; ++ct) {
    agg[ct][0] = (f32x4){0.f,0.f,0.f,0.f};
    agg[ct][1] = (f32x4){0.f,0.f,0.f,0.f};
  }
  float d[2] = {0.f, 0.f};

  // ---- chunk pipeline: stage next, compute current, drain, barrier ----
  stage64<0, 0>(smem, wsKb, wsKTb, wv, lane);
  asm volatile("s_waitcnt vmcnt(0)" ::: "memory");
  __syncthreads();

  stage64<64, 1>(smem, wsKb, wsKTb, wv, lane);
  compute64<0, 0>(smem, pbase, qf, agg, d, l15, l4);
  asm volatile("s_waitcnt vmcnt(0)" ::: "memory");
  __syncthreads();

  stage64<128, 0>(smem, wsKb, wsKTb, wv, lane);
  compute64<1, 0>(smem, pbase, qf, agg, d, l15, l4);
  asm volatile("s_waitcnt vmcnt(0)" ::: "memory");
  __syncthreads();

  stage64<192, 1>(smem, wsKb, wsKTb, wv, lane);
  compute64<0, 0>(smem, pbase, qf, agg, d, l15, l4);
  asm volatile("s_waitcnt vmcnt(0)" ::: "memory");
  __syncthreads();

  stage64<256, 0>(smem, wsKb, wsKTb, wv, lane);
  compute64<1, 0>(smem, pbase, qf, agg, d, l15, l4);
  asm volatile("s_waitcnt vmcnt(0)" ::: "memory");
  __syncthreads();

  stage64<320, 1>(smem, wsKb, wsKTb, wv, lane);
  compute64<0, 0>(smem, pbase, qf, agg, d, l15, l4);
  asm volatile("s_waitcnt vmcnt(0)" ::: "memory");
  __syncthreads();

  stage_tail(smem, wsKb, wsKTb, wv, lane);       // tail -> buf0
  compute64<1, 0>(smem, pbase, qf, agg, d, l15, l4);
  asm volatile("s_waitcnt vmcnt(0)" ::: "memory");
  __syncthreads();

  // zero VT-tail pad bytes 32..63 of each 64B row + stage W bf16 -> buf1
  {
    f32x4 z = (f32x4){0.f,0.f,0.f,0.f};
    *(f32x4*)(smem + VT_OFF + (tid >> 1) * 64 + 32 + ((tid & 1) << 4)) = z;
  }
  stage_W(smem, wsW, wv, lane);
  asm volatile("s_waitcnt vmcnt(0)" ::: "memory");
  __syncthreads();

  compute64<0, 1>(smem, pbase, qf, agg, d, l15, l4);   // tail (buf0)
  // everything below is per-wave; no more block barriers needed

  // denominator over the 4 l4-groups sharing pixel l15
  float inv[2];
  #pragma unroll
  for (int pt = 0; pt < 2; ++pt) {
    float s = d[pt];
    s += __shfl_xor(s, 16);
    s += __shfl_xor(s, 32);
    inv[pt] = 1.0f / s;
  }

  // conv in four 32-c quarters: AGG -> per-wave LDS -> mfma(W, AGG)
  f32x4 cacc[8][2];
  #pragma unroll
  for (int ot = 0; ot < 8; ++ot) {
    cacc[ot][0] = (f32x4){0.f,0.f,0.f,0.f};
    cacc[ot][1] = (f32x4){0.f,0.f,0.f,0.f};
  }
  #pragma unroll
  for (int qh = 0; qh < 4; ++qh) {
    LGKM0;                                   // prior reads of P region done
    #pragma unroll
    for (int pt = 0; pt < 2; ++pt) {
      const int prow = pt*16 + l15;
      const int sz2  = (prow & 3) << 4;
      #pragma unroll
      for (int u = 0; u < 2; ++u) {
        const f32x4 a = agg[qh*2 + u][pt];
        uint2 pk;
        pk.x = pack2(a[0] * inv[pt], a[1] * inv[pt]);
        pk.y = pack2(a[2] * inv[pt], a[3] * inv[pt]);
        *(uint2*)(pbase + prow*64 + ((u*32 + l4*8) ^ sz2)) = pk;
      }
    }
    LGKM0;
    bf16x8 agf[2];
    #pragma unroll
    for (int pt = 0; pt < 2; ++pt) {
      const int prow = pt*16 + l15;
      agf[pt] = *(const bf16x8*)(pbase + prow*64 + ((l4*16) ^ ((prow & 3) << 4)));
    }
    #pragma unroll
    for (int ot = 0; ot < 8; ++ot) {
      const bf16x8 wa = *(const bf16x8*)(smem + BUFSZ + (ot*16 + l15) * 256 +
                                         ((qh*64 + l4*16) ^ (l15 << 4)));
      cacc[ot][0] = MFMA32(wa, agf[0], cacc[ot][0], 0, 0, 0);
      cacc[ot][1] = MFMA32(wa, agf[1], cacc[ot][1], 0, 0, 0);
    }
  }

  // store: + bias + residual
  #pragma unroll
  for (int ot = 0; ot < 8; ++ot) {
    const float4 bq = *(const float4*)(b_out + ot*16 + l4*4);
    #pragma unroll
    for (int pt = 0; pt < 2; ++pt) {
      #pragma unroll
      for (int qi = 0; qi < 4; ++qi) {
        const int o = ot*16 + l4*4 + qi;
        const size_t idx = (((size_t)(b * C_N + o)) << 16) + pix0 + wv*32 + pt*16 + l15;
        out[idx] = cacc[ot][pt][qi] + ((const float*)&bq)[qi] + x5[idx];
      }
    }
  }
}

extern "C" void kernel_launch(void* const* d_in, const int* in_sizes, int n_in,
                              void* d_out, int out_size, void* d_ws, size_t ws_size,
                              hipStream_t stream) {
  const float* x5    = (const float*)d_in[0];
  const float* W_out = (const float*)d_in[1];
  const float* b_out = (const float*)d_in[2];
  float* out = (float*)d_out;
  // ws layout: wsKT first (tail staging overreads 32B past a row; lands in wsK)
  u16* wsKT = (u16*)d_ws;                                        // [4][128][400] bf16
  u16* wsK  = (u16*)((char*)d_ws + (size_t)B_N * C_N * NKP * 2); // [4][400][128] bf16
  u16* wsW  = (u16*)((char*)d_ws + (size_t)2 * B_N * C_N * NKP * 2); // [128][128] bf16

  pool_kernel<<<512, 1024, 0, stream>>>(x5, W_out, wsK, wsKT, wsW, out);

  hipFuncSetAttribute((const void*)attn_kernel,
                      hipFuncAttributeMaxDynamicSharedMemorySize, LDS_BYTES);
  attn_kernel<<<B_N * 512, 256, LDS_BYTES, stream>>>(x5, wsK, wsKT, wsW, b_out, out);
}